// Round 1
// baseline (8332.374 us; speedup 1.0000x reference)
//
#include <hip/hip_runtime.h>
#include <math.h>

#define RSQRT32 0.17677669529663687f

// colsum of the 3 We matrices -> u[3][32]
__global__ void colsum_kernel(const float* __restrict__ We, float* __restrict__ u) {
    int t = threadIdx.x;
    if (t < 96) {
        int w = t >> 5, j = t & 31;
        const float* W = We + w * 1024;
        float s = 0.f;
        #pragma unroll
        for (int kk = 0; kk < 32; ++kk) s += W[kk * 32 + j];
        u[t] = s;
    }
}

__global__ void count_kernel(const int* __restrict__ batch, int* __restrict__ cnt, int N) {
    int t = blockIdx.x * blockDim.x + threadIdx.x;
    if (t < N) atomicAdd(&cnt[batch[t]], 1);
}

// Fused q,k,v,skip GEMMs + qdotu. One wave per node-group.
// lanes 0-31: q (from xd) and v (from xs) columns; lanes 32-63: k (xs) and skip (xd).
__global__ void qkvs_kernel(
    const float* __restrict__ xs, int ssrc,
    const float* __restrict__ xd, int sdst,
    const float* __restrict__ Wq, const float* __restrict__ bq,
    const float* __restrict__ Wk, const float* __restrict__ bk,
    const float* __restrict__ Wv, const float* __restrict__ bv,
    const float* __restrict__ Ws, const float* __restrict__ bs,
    const float* __restrict__ u,      // nullptr for non-edge layers
    float* __restrict__ qb, float* __restrict__ kb,
    float* __restrict__ vb, float* __restrict__ sb,
    float* __restrict__ qdu, int N)
{
    int lane = threadIdx.x & 63;
    int wid  = __builtin_amdgcn_readfirstlane((int)(threadIdx.x >> 6));
    int wpb  = blockDim.x >> 6;
    int gw   = blockIdx.x * wpb + wid;
    int nw   = gridDim.x * wpb;
    int j    = lane & 31;
    bool lower = lane < 32;

    const float* W1 = lower ? Wq : Wk;
    const float* W2 = lower ? Wv : Ws;
    float rw1[32], rw2[32];
    #pragma unroll
    for (int kk = 0; kk < 32; ++kk) {
        rw1[kk] = W1[kk * 32 + j];
        rw2[kk] = W2[kk * 32 + j];
    }
    float bias1 = lower ? bq[j] : bk[j];
    float bias2 = lower ? bv[j] : bs[j];
    float uj = (u != nullptr) ? u[j] : 0.f;

    for (int n = gw; n < N; n += nw) {
        const float* xdr = xd + (size_t)n * sdst;  // wave-uniform -> scalar loads
        const float* xsr = xs + (size_t)n * ssrc;
        float acc1 = bias1, acc2 = bias2;
        #pragma unroll
        for (int kk = 0; kk < 32; ++kk) {
            float xdv = xdr[kk];
            float xsv = xsr[kk];
            float a  = lower ? xdv : xsv;   // q | k input
            float bb = lower ? xsv : xdv;   // v | skip input
            acc1 = fmaf(a,  rw1[kk], acc1);
            acc2 = fmaf(bb, rw2[kk], acc2);
        }
        float* o1 = lower ? qb : kb;
        float* o2 = lower ? vb : sb;
        o1[(size_t)n * 32 + j] = acc1;
        o2[(size_t)n * 32 + j] = acc2;
        if (u != nullptr) {
            float pp = lower ? acc1 * uj : 0.f;
            pp += __shfl_xor(pp, 16);
            pp += __shfl_xor(pp, 8);
            pp += __shfl_xor(pp, 4);
            pp += __shfl_xor(pp, 2);
            pp += __shfl_xor(pp, 1);
            if (lane == 0) qdu[n] = pp * RSQRT32;
        }
    }
}

// One pass per layer over edges: logit -> exp -> scatter denom & numer.
__global__ void edge_kernel(const int* __restrict__ ei, int E,
    const float* __restrict__ qb, const float* __restrict__ kb, const float* __restrict__ vb,
    const float* __restrict__ qdu, const float* __restrict__ u, const float* __restrict__ ea,
    float* __restrict__ denom, float* __restrict__ numer)
{
    int e = blockIdx.x * blockDim.x + threadIdx.x;
    if (e >= E) return;
    int s = ei[e];
    int d = ei[E + e];
    const float4* qr = (const float4*)(qb + (size_t)d * 32);
    const float4* kr = (const float4*)(kb + (size_t)s * 32);
    float dot = 0.f;
    #pragma unroll
    for (int i = 0; i < 8; ++i) {
        float4 a = qr[i], b = kr[i];
        dot += a.x*b.x + a.y*b.y + a.z*b.z + a.w*b.w;
    }
    float logit = dot * RSQRT32;
    float a_e = 0.f;
    if (ea != nullptr) {
        a_e = ea[e];
        logit += a_e * qdu[d];
    }
    float ex = __expf(logit);   // softmax shift-invariant; logits O(+-7), no overflow
    atomicAdd(&denom[d], ex);
    const float4* vr = (const float4*)(vb + (size_t)s * 32);
    float* nr = numer + (size_t)d * 32;
    if (ea != nullptr) {
        #pragma unroll
        for (int i = 0; i < 8; ++i) {
            float4 vv = vr[i];
            float4 uu = ((const float4*)u)[i];
            atomicAdd(&nr[4*i+0], (vv.x + a_e*uu.x) * ex);
            atomicAdd(&nr[4*i+1], (vv.y + a_e*uu.y) * ex);
            atomicAdd(&nr[4*i+2], (vv.z + a_e*uu.z) * ex);
            atomicAdd(&nr[4*i+3], (vv.w + a_e*uu.w) * ex);
        }
    } else {
        #pragma unroll
        for (int i = 0; i < 8; ++i) {
            float4 vv = vr[i];
            atomicAdd(&nr[4*i+0], vv.x * ex);
            atomicAdd(&nr[4*i+1], vv.y * ex);
            atomicAdd(&nr[4*i+2], vv.z * ex);
            atomicAdd(&nr[4*i+3], vv.w * ex);
        }
    }
}

// x_new = tanh(numer/denom + skip); fused mean-pool accumulation into poolsum[B,288].
__global__ void finalize_kernel(const float* __restrict__ numer, const float* __restrict__ denom,
    const float* __restrict__ skp, float* __restrict__ xout,
    const int* __restrict__ batch, float* __restrict__ poolsum, int layer_off, int N)
{
    __shared__ float red[32];
    int t = threadIdx.x;
    int idx = blockIdx.x * 256 + t;
    int n = idx >> 5, c = idx & 31;
    float val = 0.f; int b = 0;
    if (n < N) {
        float dn = denom[n];
        val = tanhf(numer[idx] / (dn + 1e-16f) + skp[idx]);
        xout[idx] = val;
        b = batch[n];
    }
    int n0 = blockIdx.x * 8;
    if (n0 >= N) return;
    int nlast = min(n0 + 7, N - 1);
    bool uniform = (batch[n0] == batch[nlast]);   // batch is sorted: usually true
    if (t < 32) red[t] = 0.f;
    __syncthreads();
    if (uniform) {
        if (n < N) atomicAdd(&red[c], val);
        __syncthreads();
        if (t < 32) atomicAdd(&poolsum[(size_t)batch[n0] * 288 + layer_off + t], red[t]);
    } else {
        if (n < N) atomicAdd(&poolsum[(size_t)b * 288 + layer_off + c], val);
    }
}

__device__ __forceinline__ void gemv_step(const float* __restrict__ W, const float* __restrict__ bias,
    const float* sin_, float* sout, int K, int M, int t, bool do_relu) {
    if (t < M) {
        float acc = bias[t];
        for (int kk = 0; kk < K; ++kk) acc = fmaf(sin_[kk], W[kk * M + t], acc);
        sout[t] = do_relu ? fmaxf(acc, 0.f) : acc;
    }
    __syncthreads();
}

// One block per graph: pooled -> W1 -> relu(W2) -> W3..W6 -> log_softmax.
// (mean-pool commutes with the W1 linear: mean(s@W1+b1) = mean(s)@W1+b1)
__global__ void head_kernel(const float* __restrict__ poolsum, const int* __restrict__ cnt,
    const float* __restrict__ W1, const float* __restrict__ b1,
    const float* __restrict__ W2, const float* __restrict__ b2,
    const float* __restrict__ W3, const float* __restrict__ b3,
    const float* __restrict__ W4, const float* __restrict__ b4,
    const float* __restrict__ W5, const float* __restrict__ b5,
    const float* __restrict__ W6, const float* __restrict__ b6,
    float* __restrict__ out)
{
    __shared__ float ha[288], hb[288];
    __shared__ float lse;
    int b = blockIdx.x, t = threadIdx.x;
    float invc = 1.f / fmaxf((float)cnt[b], 1.f);
    if (t < 288) ha[t] = poolsum[(size_t)b * 288 + t] * invc;
    __syncthreads();
    gemv_step(W1, b1, ha, hb, 288, 288, t, false);
    gemv_step(W2, b2, hb, ha, 288, 144, t, true);
    gemv_step(W3, b3, ha, hb, 144, 144, t, false);
    gemv_step(W4, b4, hb, ha, 144, 72,  t, false);
    gemv_step(W5, b5, ha, hb, 72,  72,  t, false);
    gemv_step(W6, b6, hb, ha, 72,  10,  t, false);
    if (t == 0) {
        float m = ha[0];
        for (int i = 1; i < 10; ++i) m = fmaxf(m, ha[i]);
        float ssum = 0.f;
        for (int i = 0; i < 10; ++i) ssum += __expf(ha[i] - m);
        lse = m + logf(ssum);
    }
    __syncthreads();
    if (t < 10) out[b * 10 + t] = ha[t] - lse;
}

extern "C" void kernel_launch(void* const* d_in, const int* in_sizes, int n_in,
                              void* d_out, int out_size, void* d_ws, size_t ws_size,
                              hipStream_t stream)
{
    const float* inter_emb = (const float*)d_in[0];
    const float* edge_attr = (const float*)d_in[1];
    const float* uv_emb    = (const float*)d_in[2];
    const int* inter_idx = (const int*)d_in[3];
    const int* uvt_idx   = (const int*)d_in[4];
    const int* tuv_idx   = (const int*)d_in[5];
    const int* batch     = (const int*)d_in[6];
    const float* cWq = (const float*)d_in[7];  const float* cbq = (const float*)d_in[8];
    const float* cWk = (const float*)d_in[9];  const float* cbk = (const float*)d_in[10];
    const float* cWv = (const float*)d_in[11]; const float* cbv = (const float*)d_in[12];
    const float* cWs = (const float*)d_in[13]; const float* cbs = (const float*)d_in[14];
    const float* cWe = (const float*)d_in[15];
    const float* W1 = (const float*)d_in[16]; const float* b1 = (const float*)d_in[17];
    const float* W2 = (const float*)d_in[18]; const float* b2 = (const float*)d_in[19];
    const float* W3 = (const float*)d_in[20]; const float* b3 = (const float*)d_in[21];
    const float* W4 = (const float*)d_in[22]; const float* b4 = (const float*)d_in[23];
    const float* W5 = (const float*)d_in[24]; const float* b5 = (const float*)d_in[25];
    const float* W6 = (const float*)d_in[26]; const float* b6 = (const float*)d_in[27];

    const int N = in_sizes[2] / 32;
    const int E = in_sizes[1];
    const int B = out_size / 10;

    char* p = (char*)d_ws;
    auto alloc = [&](size_t bytes) { char* r = p; p += (bytes + 255) & ~(size_t)255; return r; };
    float* qb    = (float*)alloc((size_t)N * 32 * 4);
    float* kb    = (float*)alloc((size_t)N * 32 * 4);
    float* vb    = (float*)alloc((size_t)N * 32 * 4);
    float* sb    = (float*)alloc((size_t)N * 32 * 4);
    float* qdu   = (float*)alloc((size_t)N * 4);
    float* denom = (float*)alloc((size_t)N * 4 + (size_t)N * 32 * 4);  // denom | numer contiguous
    float* numer = denom + N;
    float* xa    = (float*)alloc((size_t)N * 32 * 4);
    float* xb    = (float*)alloc((size_t)N * 32 * 4);
    float* ub    = (float*)alloc(96 * 4);
    float* poolsum = (float*)alloc((size_t)B * 288 * 4);
    int*   cnt   = (int*)alloc((size_t)B * 4);

    hipMemsetAsync(poolsum, 0, (size_t)B * 288 * 4, stream);
    hipMemsetAsync(cnt, 0, (size_t)B * 4, stream);
    colsum_kernel<<<1, 128, 0, stream>>>(cWe, ub);
    count_kernel<<<(N + 255) / 256, 256, 0, stream>>>(batch, cnt, N);

    const int* eidx[3] = {inter_idx, uvt_idx, tuv_idx};
    float* xcur = nullptr;
    float* xnext = xa;
    for (int i = 0; i < 9; ++i) {
        int r = i % 3;
        const float* xsrc; int ssrc; const float* xdst; int sdst;
        if (i == 0)      { xsrc = inter_emb; ssrc = 64; xdst = inter_emb + 32; sdst = 64; }
        else if (r == 0) { xsrc = xcur; ssrc = 32; xdst = xcur;  sdst = 32; }
        else if (r == 1) { xsrc = xcur; ssrc = 32; xdst = uv_emb; sdst = 32; }
        else             { xsrc = uv_emb; ssrc = 32; xdst = xcur; sdst = 32; }
        const float* ul = (r == 0) ? (ub + (i / 3) * 32) : nullptr;
        const float* ea = (r == 0) ? edge_attr : nullptr;

        hipMemsetAsync(denom, 0, (size_t)N * 4 + (size_t)N * 32 * 4, stream);
        qkvs_kernel<<<1024, 256, 0, stream>>>(xsrc, ssrc, xdst, sdst,
            cWq + i * 1024, cbq + i * 32, cWk + i * 1024, cbk + i * 32,
            cWv + i * 1024, cbv + i * 32, cWs + i * 1024, cbs + i * 32,
            ul, qb, kb, vb, sb, qdu, N);
        edge_kernel<<<(E + 255) / 256, 256, 0, stream>>>(eidx[r], E, qb, kb, vb, qdu, ul, ea, denom, numer);
        finalize_kernel<<<(N * 32 + 255) / 256, 256, 0, stream>>>(numer, denom, sb, xnext, batch, poolsum, i * 32, N);
        xcur = xnext;
        xnext = (xnext == xa) ? xb : xa;
    }

    head_kernel<<<B, 320, 0, stream>>>(poolsum, cnt,
        W1, b1, W2, b2, W3, b3, W4, b4, W5, b5, W6, b6, (float*)d_out);
}

// Round 2
// 1241.138 us; speedup vs baseline: 6.7135x; 6.7135x over previous
//
#include <hip/hip_runtime.h>
#include <math.h>

#define RSQRT32 0.17677669529663687f

// ---------------- CSR build (once per call; 3 relations concurrently) ----------------

__global__ void hist_all(const int* __restrict__ e0, const int* __restrict__ e1,
                         const int* __restrict__ e2, int E, int* __restrict__ cnt3, int N) {
    int t = blockIdx.x * blockDim.x + threadIdx.x;
    if (t >= 3 * E) return;
    int r = t / E, e = t - r * E;
    const int* ei = (r == 0) ? e0 : ((r == 1) ? e1 : e2);
    atomicAdd(&cnt3[r * N + ei[E + e]], 1);
}

// 3 blocks (one per relation); blocked per-thread serial + one 1024-wide scan.
__global__ void scan_all(const int* __restrict__ cnt3, int* __restrict__ rp3, int N) {
    __shared__ int part[1024];
    int r = blockIdx.x, t = threadIdx.x;
    const int* cnt = cnt3 + (size_t)r * N;
    int* rp = rp3 + (size_t)r * (N + 1);
    int per = (N + 1023) >> 10;
    int beg = t * per, end = min(beg + per, N);
    int s = 0;
    for (int i = beg; i < end; ++i) s += cnt[i];
    part[t] = s;
    __syncthreads();
    for (int off = 1; off < 1024; off <<= 1) {
        int x = (t >= off) ? part[t - off] : 0;
        __syncthreads();
        part[t] += x;
        __syncthreads();
    }
    int run = part[t] - s;   // exclusive prefix of this thread's chunk
    for (int i = beg; i < end; ++i) { rp[i] = run; run += cnt[i]; }
    if (t == 1023) rp[N] = part[1023];
}

__global__ void init_cursor(const int* __restrict__ rp3, int* __restrict__ cur3, int N) {
    int t = blockIdx.x * blockDim.x + threadIdx.x;
    if (t >= 3 * N) return;
    int r = t / N, i = t - r * N;
    cur3[t] = rp3[r * (N + 1) + i];
}

// adj payload: .x = src node, .y = bitcast(edge_attr) for relation 0 else 0
__global__ void scatter_all(const int* __restrict__ e0, const int* __restrict__ e1,
                            const int* __restrict__ e2, const float* __restrict__ ea,
                            int E, int* __restrict__ cur3, int2* __restrict__ adj3, int N) {
    int t = blockIdx.x * blockDim.x + threadIdx.x;
    if (t >= 3 * E) return;
    int r = t / E, e = t - r * E;
    const int* ei = (r == 0) ? e0 : ((r == 1) ? e1 : e2);
    int s = ei[e], d = ei[E + e];
    int pos = atomicAdd(&cur3[r * N + d], 1);
    int2 v;
    v.x = s;
    v.y = (r == 0) ? __float_as_int(ea[e]) : 0;
    adj3[(size_t)r * E + pos] = v;
}

// ---------------- misc small kernels ----------------

__global__ void colsum_kernel(const float* __restrict__ We, float* __restrict__ u) {
    int t = threadIdx.x;
    if (t < 96) {
        int w = t >> 5, j = t & 31;
        const float* W = We + w * 1024;
        float s = 0.f;
        #pragma unroll
        for (int kk = 0; kk < 32; ++kk) s += W[kk * 32 + j];
        u[t] = s;
    }
}

__global__ void count_kernel(const int* __restrict__ batch, int* __restrict__ cnt, int N) {
    int t = blockIdx.x * blockDim.x + threadIdx.x;
    if (t < N) atomicAdd(&cnt[batch[t]], 1);
}

// ---------------- per-layer: fused q,k,v,skip GEMMs (+qdotu) ----------------
// lanes 0-31: q (xd) & v (xs) columns; lanes 32-63: k (xs) & skip (xd) columns.
// k,v written interleaved into kv[n][64] = [k(32) | v(32)] for gather locality.
__global__ void qkvs_kernel(
    const float* __restrict__ xs, int ssrc,
    const float* __restrict__ xd, int sdst,
    const float* __restrict__ Wq, const float* __restrict__ bq,
    const float* __restrict__ Wk, const float* __restrict__ bk,
    const float* __restrict__ Wv, const float* __restrict__ bv,
    const float* __restrict__ Ws, const float* __restrict__ bs,
    const float* __restrict__ u,      // nullptr for non-edge layers
    float* __restrict__ qb, float* __restrict__ kv,
    float* __restrict__ sb, float* __restrict__ qdu, int N)
{
    int lane = threadIdx.x & 63;
    int wid  = __builtin_amdgcn_readfirstlane((int)(threadIdx.x >> 6));
    int wpb  = blockDim.x >> 6;
    int gw   = blockIdx.x * wpb + wid;
    int nw   = gridDim.x * wpb;
    int j    = lane & 31;
    bool lower = lane < 32;

    const float* W1 = lower ? Wq : Wk;
    const float* W2 = lower ? Wv : Ws;
    float rw1[32], rw2[32];
    #pragma unroll
    for (int kk = 0; kk < 32; ++kk) {
        rw1[kk] = W1[kk * 32 + j];
        rw2[kk] = W2[kk * 32 + j];
    }
    float bias1 = lower ? bq[j] : bk[j];
    float bias2 = lower ? bv[j] : bs[j];
    float uj = (u != nullptr) ? u[j] : 0.f;

    for (int n = gw; n < N; n += nw) {
        const float* xdr = xd + (size_t)n * sdst;  // wave-uniform -> scalar loads
        const float* xsr = xs + (size_t)n * ssrc;
        float acc1 = bias1, acc2 = bias2;
        #pragma unroll
        for (int kk = 0; kk < 32; ++kk) {
            float xdv = xdr[kk];
            float xsv = xsr[kk];
            float a  = lower ? xdv : xsv;   // q | k input
            float bb = lower ? xsv : xdv;   // v | skip input
            acc1 = fmaf(a,  rw1[kk], acc1);
            acc2 = fmaf(bb, rw2[kk], acc2);
        }
        if (lower) {
            qb[(size_t)n * 32 + j] = acc1;          // q
            kv[(size_t)n * 64 + 32 + j] = acc2;     // v
        } else {
            kv[(size_t)n * 64 + j] = acc1;          // k
            sb[(size_t)n * 32 + j] = acc2;          // skip
        }
        if (u != nullptr) {
            float pp = lower ? acc1 * uj : 0.f;
            pp += __shfl_xor(pp, 16);
            pp += __shfl_xor(pp, 8);
            pp += __shfl_xor(pp, 4);
            pp += __shfl_xor(pp, 2);
            pp += __shfl_xor(pp, 1);
            if (lane == 0) qdu[n] = pp * RSQRT32;
        }
    }
}

// ---------------- per-layer: gather-side aggregation, no atomics ----------------
// One 32-lane half-wave per destination node; lane c owns channel c.
// Fuses softmax-weighted aggregation + skip + tanh + mean-pool accumulation.
__global__ void agg_kernel(const int* __restrict__ rp, const int2* __restrict__ adj,
    const float* __restrict__ qb, const float* __restrict__ kv,
    const float* __restrict__ qdu, const float* __restrict__ u,
    const float* __restrict__ skp, float* __restrict__ xout,
    const int* __restrict__ batch, float* __restrict__ poolsum,
    int layer_off, int N, int has_ea)
{
    __shared__ float red[32];
    int t = threadIdx.x;
    int h = t >> 5, c = t & 31;
    int n = blockIdx.x * 8 + h;
    float val = 0.f;
    int b = 0;
    if (n < N) {
        float qc = qb[(size_t)n * 32 + c];
        float qd = has_ea ? qdu[n] : 0.f;
        float uc = has_ea ? u[c] : 0.f;
        int beg = rp[n], end = rp[n + 1];
        float denom = 1e-16f, num = 0.f;
        for (int i = beg; i < end; ++i) {
            int2 sv = adj[i];
            const float* kvr = kv + (size_t)sv.x * 64;
            float kc = kvr[c];
            float vc = kvr[32 + c];
            float dot = qc * kc;
            dot += __shfl_xor(dot, 16);
            dot += __shfl_xor(dot, 8);
            dot += __shfl_xor(dot, 4);
            dot += __shfl_xor(dot, 2);
            dot += __shfl_xor(dot, 1);
            float ae = has_ea ? __int_as_float(sv.y) : 0.f;
            // softmax is shift-invariant; logits O(+-7) so direct exp is safe
            float ex = __expf(fmaf(ae, qd, dot * RSQRT32));
            denom += ex;
            num = fmaf(fmaf(ae, uc, vc), ex, num);
        }
        val = tanhf(num / denom + skp[(size_t)n * 32 + c]);
        xout[(size_t)n * 32 + c] = val;
        b = batch[n];
    }
    // mean-pool accumulation (batch is sorted: blocks are usually batch-uniform)
    int n0 = blockIdx.x * 8;
    if (n0 >= N) return;
    int nlast = min(n0 + 7, N - 1);
    bool uniform = (batch[n0] == batch[nlast]);
    if (t < 32) red[t] = 0.f;
    __syncthreads();
    if (uniform) {
        if (n < N) atomicAdd(&red[c], val);
        __syncthreads();
        if (t < 32) atomicAdd(&poolsum[(size_t)batch[n0] * 288 + layer_off + t], red[t]);
    } else {
        if (n < N) atomicAdd(&poolsum[(size_t)b * 288 + layer_off + c], val);
    }
}

// ---------------- head ----------------

__device__ __forceinline__ void gemv_step(const float* __restrict__ W, const float* __restrict__ bias,
    const float* sin_, float* sout, int K, int M, int t, bool do_relu) {
    if (t < M) {
        float acc = bias[t];
        for (int kk = 0; kk < K; ++kk) acc = fmaf(sin_[kk], W[kk * M + t], acc);
        sout[t] = do_relu ? fmaxf(acc, 0.f) : acc;
    }
    __syncthreads();
}

// One block per graph. (mean-pool commutes with W1: mean(s@W1+b1) = mean(s)@W1+b1)
__global__ void head_kernel(const float* __restrict__ poolsum, const int* __restrict__ cnt,
    const float* __restrict__ W1, const float* __restrict__ b1,
    const float* __restrict__ W2, const float* __restrict__ b2,
    const float* __restrict__ W3, const float* __restrict__ b3,
    const float* __restrict__ W4, const float* __restrict__ b4,
    const float* __restrict__ W5, const float* __restrict__ b5,
    const float* __restrict__ W6, const float* __restrict__ b6,
    float* __restrict__ out)
{
    __shared__ float ha[288], hb[288];
    __shared__ float lse;
    int b = blockIdx.x, t = threadIdx.x;
    float invc = 1.f / fmaxf((float)cnt[b], 1.f);
    if (t < 288) ha[t] = poolsum[(size_t)b * 288 + t] * invc;
    __syncthreads();
    gemv_step(W1, b1, ha, hb, 288, 288, t, false);
    gemv_step(W2, b2, hb, ha, 288, 144, t, true);
    gemv_step(W3, b3, ha, hb, 144, 144, t, false);
    gemv_step(W4, b4, hb, ha, 144, 72,  t, false);
    gemv_step(W5, b5, ha, hb, 72,  72,  t, false);
    gemv_step(W6, b6, hb, ha, 72,  10,  t, false);
    if (t == 0) {
        float m = ha[0];
        for (int i = 1; i < 10; ++i) m = fmaxf(m, ha[i]);
        float ssum = 0.f;
        for (int i = 0; i < 10; ++i) ssum += __expf(ha[i] - m);
        lse = m + logf(ssum);
    }
    __syncthreads();
    if (t < 10) out[b * 10 + t] = ha[t] - lse;
}

// ---------------- launch ----------------

extern "C" void kernel_launch(void* const* d_in, const int* in_sizes, int n_in,
                              void* d_out, int out_size, void* d_ws, size_t ws_size,
                              hipStream_t stream)
{
    const float* inter_emb = (const float*)d_in[0];
    const float* edge_attr = (const float*)d_in[1];
    const float* uv_emb    = (const float*)d_in[2];
    const int* inter_idx = (const int*)d_in[3];
    const int* uvt_idx   = (const int*)d_in[4];
    const int* tuv_idx   = (const int*)d_in[5];
    const int* batch     = (const int*)d_in[6];
    const float* cWq = (const float*)d_in[7];  const float* cbq = (const float*)d_in[8];
    const float* cWk = (const float*)d_in[9];  const float* cbk = (const float*)d_in[10];
    const float* cWv = (const float*)d_in[11]; const float* cbv = (const float*)d_in[12];
    const float* cWs = (const float*)d_in[13]; const float* cbs = (const float*)d_in[14];
    const float* cWe = (const float*)d_in[15];
    const float* W1 = (const float*)d_in[16]; const float* b1 = (const float*)d_in[17];
    const float* W2 = (const float*)d_in[18]; const float* b2 = (const float*)d_in[19];
    const float* W3 = (const float*)d_in[20]; const float* b3 = (const float*)d_in[21];
    const float* W4 = (const float*)d_in[22]; const float* b4 = (const float*)d_in[23];
    const float* W5 = (const float*)d_in[24]; const float* b5 = (const float*)d_in[25];
    const float* W6 = (const float*)d_in[26]; const float* b6 = (const float*)d_in[27];

    const int N = in_sizes[2] / 32;
    const int E = in_sizes[1];
    const int B = out_size / 10;

    char* p = (char*)d_ws;
    auto alloc = [&](size_t bytes) { char* r = p; p += (bytes + 255) & ~(size_t)255; return r; };
    float* qb    = (float*)alloc((size_t)N * 32 * 4);
    float* kv    = (float*)alloc((size_t)N * 64 * 4);   // interleaved [k|v] per node
    float* sb    = (float*)alloc((size_t)N * 32 * 4);
    float* qdu   = (float*)alloc((size_t)N * 4);
    float* xa    = (float*)alloc((size_t)N * 32 * 4);
    float* xb    = (float*)alloc((size_t)N * 32 * 4);
    float* ub    = (float*)alloc(96 * 4);
    float* poolsum = (float*)alloc((size_t)B * 288 * 4);
    int*   cnt   = (int*)alloc((size_t)B * 4);
    int*   cnt3  = (int*)alloc((size_t)3 * N * 4);      // histogram, then cursor
    int*   rp3   = (int*)alloc((size_t)3 * (N + 1) * 4);
    int2*  adj3  = (int2*)alloc((size_t)3 * E * 8);

    // ---- CSR build (topology fixed; reused by 3 layers each) ----
    hipMemsetAsync(cnt3, 0, (size_t)3 * N * 4, stream);
    hist_all<<<(3 * E + 255) / 256, 256, 0, stream>>>(inter_idx, uvt_idx, tuv_idx, E, cnt3, N);
    scan_all<<<3, 1024, 0, stream>>>(cnt3, rp3, N);
    init_cursor<<<(3 * N + 255) / 256, 256, 0, stream>>>(rp3, cnt3, N);  // cnt3 becomes cursor
    scatter_all<<<(3 * E + 255) / 256, 256, 0, stream>>>(inter_idx, uvt_idx, tuv_idx,
                                                         edge_attr, E, cnt3, adj3, N);

    hipMemsetAsync(poolsum, 0, (size_t)B * 288 * 4, stream);
    hipMemsetAsync(cnt, 0, (size_t)B * 4, stream);
    colsum_kernel<<<1, 128, 0, stream>>>(cWe, ub);
    count_kernel<<<(N + 255) / 256, 256, 0, stream>>>(batch, cnt, N);

    float* xcur = nullptr;
    float* xnext = xa;
    for (int i = 0; i < 9; ++i) {
        int r = i % 3;
        const float* xsrc; int ssrc; const float* xdst; int sdst;
        if (i == 0)      { xsrc = inter_emb; ssrc = 64; xdst = inter_emb + 32; sdst = 64; }
        else if (r == 0) { xsrc = xcur; ssrc = 32; xdst = xcur;  sdst = 32; }
        else if (r == 1) { xsrc = xcur; ssrc = 32; xdst = uv_emb; sdst = 32; }
        else             { xsrc = uv_emb; ssrc = 32; xdst = xcur; sdst = 32; }
        const float* ul = (r == 0) ? (ub + (i / 3) * 32) : nullptr;

        qkvs_kernel<<<1024, 256, 0, stream>>>(xsrc, ssrc, xdst, sdst,
            cWq + i * 1024, cbq + i * 32, cWk + i * 1024, cbk + i * 32,
            cWv + i * 1024, cbv + i * 32, cWs + i * 1024, cbs + i * 32,
            ul, qb, kv, sb, qdu, N);
        agg_kernel<<<(N + 7) / 8, 256, 0, stream>>>(
            rp3 + (size_t)r * (N + 1), adj3 + (size_t)r * E,
            qb, kv, qdu, ul, sb, xnext, batch, poolsum, i * 32, N, (r == 0) ? 1 : 0);
        xcur = xnext;
        xnext = (xnext == xa) ? xb : xa;
    }

    head_kernel<<<B, 320, 0, stream>>>(poolsum, cnt,
        W1, b1, W2, b2, W3, b3, W4, b4, W5, b5, W6, b6, (float*)d_out);
}

// Round 3
// 886.749 us; speedup vs baseline: 9.3965x; 1.3996x over previous
//
#include <hip/hip_runtime.h>
#include <math.h>

#define RSQRT32 0.17677669529663687f

// ---------------- CSR build (once per call; 3 relations concurrently) ----------------

__global__ void hist_all(const int* __restrict__ e0, const int* __restrict__ e1,
                         const int* __restrict__ e2, int E, int* __restrict__ cnt3, int N) {
    int t = blockIdx.x * blockDim.x + threadIdx.x;
    if (t >= 3 * E) return;
    int r = t / E, e = t - r * E;
    const int* ei = (r == 0) ? e0 : ((r == 1) ? e1 : e2);
    atomicAdd(&cnt3[r * N + ei[E + e]], 1);
}

// 3 blocks (one per relation); blocked per-thread serial + one 1024-wide scan.
__global__ void scan_all(const int* __restrict__ cnt3, int* __restrict__ rp3, int N) {
    __shared__ int part[1024];
    int r = blockIdx.x, t = threadIdx.x;
    const int* cnt = cnt3 + (size_t)r * N;
    int* rp = rp3 + (size_t)r * (N + 1);
    int per = (N + 1023) >> 10;
    int beg = t * per, end = min(beg + per, N);
    int s = 0;
    for (int i = beg; i < end; ++i) s += cnt[i];
    part[t] = s;
    __syncthreads();
    for (int off = 1; off < 1024; off <<= 1) {
        int x = (t >= off) ? part[t - off] : 0;
        __syncthreads();
        part[t] += x;
        __syncthreads();
    }
    int run = part[t] - s;   // exclusive prefix of this thread's chunk
    for (int i = beg; i < end; ++i) { rp[i] = run; run += cnt[i]; }
    if (t == 1023) rp[N] = part[1023];
}

__global__ void init_cursor(const int* __restrict__ rp3, int* __restrict__ cur3, int N) {
    int t = blockIdx.x * blockDim.x + threadIdx.x;
    if (t >= 3 * N) return;
    int r = t / N, i = t - r * N;
    cur3[t] = rp3[r * (N + 1) + i];
}

// adj payload: .x = src node, .y = bitcast(edge_attr) for relation 0 else 0
__global__ void scatter_all(const int* __restrict__ e0, const int* __restrict__ e1,
                            const int* __restrict__ e2, const float* __restrict__ ea,
                            int E, int* __restrict__ cur3, int2* __restrict__ adj3, int N) {
    int t = blockIdx.x * blockDim.x + threadIdx.x;
    if (t >= 3 * E) return;
    int r = t / E, e = t - r * E;
    const int* ei = (r == 0) ? e0 : ((r == 1) ? e1 : e2);
    int s = ei[e], d = ei[E + e];
    int pos = atomicAdd(&cur3[r * N + d], 1);
    int2 v;
    v.x = s;
    v.y = (r == 0) ? __float_as_int(ea[e]) : 0;
    adj3[(size_t)r * E + pos] = v;
}

// ---------------- misc small kernels ----------------

__global__ void colsum_kernel(const float* __restrict__ We, float* __restrict__ u) {
    int t = threadIdx.x;
    if (t < 96) {
        int w = t >> 5, j = t & 31;
        const float* W = We + w * 1024;
        float s = 0.f;
        #pragma unroll
        for (int kk = 0; kk < 32; ++kk) s += W[kk * 32 + j];
        u[t] = s;
    }
}

// batch is sorted: graph sizes are run lengths -> plain unique stores, no atomics.
__global__ void bounds_kernel(const int* __restrict__ batch, int* __restrict__ bstart,
                              int* __restrict__ bend, int N) {
    int t = blockIdx.x * blockDim.x + threadIdx.x;
    if (t >= N) return;
    int b = batch[t];
    if (t == 0 || batch[t - 1] != b) bstart[b] = t;
    if (t == N - 1 || batch[t + 1] != b) bend[b] = t + 1;
}

// ---------------- per-layer: fused q,k,v,skip GEMMs (+qdotu) ----------------
// lanes 0-31: q (xd) & v (xs) columns; lanes 32-63: k (xs) & skip (xd) columns.
// k,v written per-channel interleaved: kv[n][2c]=k_c, kv[n][2c+1]=v_c (float2 gathers).
__global__ void qkvs_kernel(
    const float* __restrict__ xs, int ssrc,
    const float* __restrict__ xd, int sdst,
    const float* __restrict__ Wq, const float* __restrict__ bq,
    const float* __restrict__ Wk, const float* __restrict__ bk,
    const float* __restrict__ Wv, const float* __restrict__ bv,
    const float* __restrict__ Ws, const float* __restrict__ bs,
    const float* __restrict__ u,      // nullptr for non-edge layers
    float* __restrict__ qb, float* __restrict__ kv,
    float* __restrict__ sb, float* __restrict__ qdu, int N)
{
    int lane = threadIdx.x & 63;
    int wid  = __builtin_amdgcn_readfirstlane((int)(threadIdx.x >> 6));
    int wpb  = blockDim.x >> 6;
    int gw   = blockIdx.x * wpb + wid;
    int nw   = gridDim.x * wpb;
    int j    = lane & 31;
    bool lower = lane < 32;

    const float* W1 = lower ? Wq : Wk;
    const float* W2 = lower ? Wv : Ws;
    float rw1[32], rw2[32];
    #pragma unroll
    for (int kk = 0; kk < 32; ++kk) {
        rw1[kk] = W1[kk * 32 + j];
        rw2[kk] = W2[kk * 32 + j];
    }
    float bias1 = lower ? bq[j] : bk[j];
    float bias2 = lower ? bv[j] : bs[j];
    float uj = (u != nullptr) ? u[j] : 0.f;

    for (int n = gw; n < N; n += nw) {
        const float* xdr = xd + (size_t)n * sdst;  // wave-uniform -> scalar loads
        const float* xsr = xs + (size_t)n * ssrc;
        float acc1 = bias1, acc2 = bias2;
        #pragma unroll
        for (int kk = 0; kk < 32; ++kk) {
            float xdv = xdr[kk];
            float xsv = xsr[kk];
            float a  = lower ? xdv : xsv;   // q | k input
            float bb = lower ? xsv : xdv;   // v | skip input
            acc1 = fmaf(a,  rw1[kk], acc1);
            acc2 = fmaf(bb, rw2[kk], acc2);
        }
        if (lower) {
            qb[(size_t)n * 32 + j] = acc1;          // q
            kv[(size_t)n * 64 + 2 * j + 1] = acc2;  // v
        } else {
            kv[(size_t)n * 64 + 2 * j] = acc1;      // k
            sb[(size_t)n * 32 + j] = acc2;          // skip
        }
        if (u != nullptr) {
            float pp = lower ? acc1 * uj : 0.f;
            pp += __shfl_xor(pp, 16);
            pp += __shfl_xor(pp, 8);
            pp += __shfl_xor(pp, 4);
            pp += __shfl_xor(pp, 2);
            pp += __shfl_xor(pp, 1);
            if (lane == 0) qdu[n] = pp * RSQRT32;
        }
    }
}

// ---------------- per-layer: gather-side aggregation, no atomics ----------------
// One 32-lane half-wave per destination node; lane c owns channel c.
// 2-way edge unroll: two independent gather/reduce streams hide L2/L3 latency.
// Fuses softmax-weighted aggregation + skip + tanh + mean-pool accumulation.
__global__ void agg_kernel(const int* __restrict__ rp, const int2* __restrict__ adj,
    const float* __restrict__ qb, const float* __restrict__ kv,
    const float* __restrict__ qdu, const float* __restrict__ u,
    const float* __restrict__ skp, float* __restrict__ xout,
    const int* __restrict__ batch, float* __restrict__ poolsum,
    int layer_off, int N, int has_ea)
{
    __shared__ float red[32];
    int t = threadIdx.x;
    int h = t >> 5, c = t & 31;
    int n = blockIdx.x * 8 + h;
    float val = 0.f;
    int b = 0;
    if (n < N) {
        float qc = qb[(size_t)n * 32 + c];
        float qd = has_ea ? qdu[n] : 0.f;
        float uc = has_ea ? u[c] : 0.f;
        int beg = rp[n], end = rp[n + 1];
        float den0 = 1e-16f, num0 = 0.f, den1 = 0.f, num1 = 0.f;
        int i = beg;
        for (; i + 1 < end; i += 2) {
            int2 sv0 = adj[i];
            int2 sv1 = adj[i + 1];
            float2 kv0 = ((const float2*)(kv + (size_t)sv0.x * 64))[c];
            float2 kv1 = ((const float2*)(kv + (size_t)sv1.x * 64))[c];
            float d0 = qc * kv0.x;
            float d1 = qc * kv1.x;
            d0 += __shfl_xor(d0, 16); d1 += __shfl_xor(d1, 16);
            d0 += __shfl_xor(d0, 8);  d1 += __shfl_xor(d1, 8);
            d0 += __shfl_xor(d0, 4);  d1 += __shfl_xor(d1, 4);
            d0 += __shfl_xor(d0, 2);  d1 += __shfl_xor(d1, 2);
            d0 += __shfl_xor(d0, 1);  d1 += __shfl_xor(d1, 1);
            float ae0 = has_ea ? __int_as_float(sv0.y) : 0.f;
            float ae1 = has_ea ? __int_as_float(sv1.y) : 0.f;
            // softmax is shift-invariant; logits O(+-7) so direct exp is safe
            float ex0 = __expf(fmaf(ae0, qd, d0 * RSQRT32));
            float ex1 = __expf(fmaf(ae1, qd, d1 * RSQRT32));
            den0 += ex0;                den1 += ex1;
            num0 = fmaf(fmaf(ae0, uc, kv0.y), ex0, num0);
            num1 = fmaf(fmaf(ae1, uc, kv1.y), ex1, num1);
        }
        if (i < end) {
            int2 sv = adj[i];
            float2 kvc = ((const float2*)(kv + (size_t)sv.x * 64))[c];
            float d0 = qc * kvc.x;
            d0 += __shfl_xor(d0, 16);
            d0 += __shfl_xor(d0, 8);
            d0 += __shfl_xor(d0, 4);
            d0 += __shfl_xor(d0, 2);
            d0 += __shfl_xor(d0, 1);
            float ae = has_ea ? __int_as_float(sv.y) : 0.f;
            float ex = __expf(fmaf(ae, qd, d0 * RSQRT32));
            den0 += ex;
            num0 = fmaf(fmaf(ae, uc, kvc.y), ex, num0);
        }
        float denom = den0 + den1, num = num0 + num1;
        val = tanhf(num / denom + skp[(size_t)n * 32 + c]);
        xout[(size_t)n * 32 + c] = val;
        b = batch[n];
    }
    // mean-pool accumulation (batch is sorted: blocks are usually batch-uniform)
    int n0 = blockIdx.x * 8;
    if (n0 >= N) return;
    int nlast = min(n0 + 7, N - 1);
    bool uniform = (batch[n0] == batch[nlast]);
    if (t < 32) red[t] = 0.f;
    __syncthreads();
    if (uniform) {
        if (n < N) atomicAdd(&red[c], val);
        __syncthreads();
        if (t < 32) atomicAdd(&poolsum[(size_t)batch[n0] * 288 + layer_off + t], red[t]);
    } else {
        if (n < N) atomicAdd(&poolsum[(size_t)b * 288 + layer_off + c], val);
    }
}

// ---------------- head ----------------

__device__ __forceinline__ void gemv_step(const float* __restrict__ W, const float* __restrict__ bias,
    const float* sin_, float* sout, int K, int M, int t, bool do_relu) {
    if (t < M) {
        float acc = bias[t];
        for (int kk = 0; kk < K; ++kk) acc = fmaf(sin_[kk], W[kk * M + t], acc);
        sout[t] = do_relu ? fmaxf(acc, 0.f) : acc;
    }
    __syncthreads();
}

// One block per graph. (mean-pool commutes with W1: mean(s@W1+b1) = mean(s)@W1+b1)
__global__ void head_kernel(const float* __restrict__ poolsum,
    const int* __restrict__ bstart, const int* __restrict__ bend,
    const float* __restrict__ W1, const float* __restrict__ b1,
    const float* __restrict__ W2, const float* __restrict__ b2,
    const float* __restrict__ W3, const float* __restrict__ b3,
    const float* __restrict__ W4, const float* __restrict__ b4,
    const float* __restrict__ W5, const float* __restrict__ b5,
    const float* __restrict__ W6, const float* __restrict__ b6,
    float* __restrict__ out)
{
    __shared__ float ha[288], hb[288];
    __shared__ float lse;
    int b = blockIdx.x, t = threadIdx.x;
    float invc = 1.f / fmaxf((float)(bend[b] - bstart[b]), 1.f);
    if (t < 288) ha[t] = poolsum[(size_t)b * 288 + t] * invc;
    __syncthreads();
    gemv_step(W1, b1, ha, hb, 288, 288, t, false);
    gemv_step(W2, b2, hb, ha, 288, 144, t, true);
    gemv_step(W3, b3, ha, hb, 144, 144, t, false);
    gemv_step(W4, b4, hb, ha, 144, 72,  t, false);
    gemv_step(W5, b5, ha, hb, 72,  72,  t, false);
    gemv_step(W6, b6, hb, ha, 72,  10,  t, false);
    if (t == 0) {
        float m = ha[0];
        for (int i = 1; i < 10; ++i) m = fmaxf(m, ha[i]);
        float ssum = 0.f;
        for (int i = 0; i < 10; ++i) ssum += __expf(ha[i] - m);
        lse = m + logf(ssum);
    }
    __syncthreads();
    if (t < 10) out[b * 10 + t] = ha[t] - lse;
}

// ---------------- launch ----------------

extern "C" void kernel_launch(void* const* d_in, const int* in_sizes, int n_in,
                              void* d_out, int out_size, void* d_ws, size_t ws_size,
                              hipStream_t stream)
{
    const float* inter_emb = (const float*)d_in[0];
    const float* edge_attr = (const float*)d_in[1];
    const float* uv_emb    = (const float*)d_in[2];
    const int* inter_idx = (const int*)d_in[3];
    const int* uvt_idx   = (const int*)d_in[4];
    const int* tuv_idx   = (const int*)d_in[5];
    const int* batch     = (const int*)d_in[6];
    const float* cWq = (const float*)d_in[7];  const float* cbq = (const float*)d_in[8];
    const float* cWk = (const float*)d_in[9];  const float* cbk = (const float*)d_in[10];
    const float* cWv = (const float*)d_in[11]; const float* cbv = (const float*)d_in[12];
    const float* cWs = (const float*)d_in[13]; const float* cbs = (const float*)d_in[14];
    const float* cWe = (const float*)d_in[15];
    const float* W1 = (const float*)d_in[16]; const float* b1 = (const float*)d_in[17];
    const float* W2 = (const float*)d_in[18]; const float* b2 = (const float*)d_in[19];
    const float* W3 = (const float*)d_in[20]; const float* b3 = (const float*)d_in[21];
    const float* W4 = (const float*)d_in[22]; const float* b4 = (const float*)d_in[23];
    const float* W5 = (const float*)d_in[24]; const float* b5 = (const float*)d_in[25];
    const float* W6 = (const float*)d_in[26]; const float* b6 = (const float*)d_in[27];

    const int N = in_sizes[2] / 32;
    const int E = in_sizes[1];
    const int B = out_size / 10;

    char* p = (char*)d_ws;
    auto alloc = [&](size_t bytes) { char* r = p; p += (bytes + 255) & ~(size_t)255; return r; };
    float* qb    = (float*)alloc((size_t)N * 32 * 4);
    float* kv    = (float*)alloc((size_t)N * 64 * 4);   // per-channel interleaved (k,v) float2
    float* sb    = (float*)alloc((size_t)N * 32 * 4);
    float* qdu   = (float*)alloc((size_t)N * 4);
    float* xa    = (float*)alloc((size_t)N * 32 * 4);
    float* xb    = (float*)alloc((size_t)N * 32 * 4);
    float* ub    = (float*)alloc(96 * 4);
    float* poolsum = (float*)alloc((size_t)B * 288 * 4);
    int*   bstart = (int*)alloc((size_t)B * 4);
    int*   bend   = (int*)alloc((size_t)B * 4);
    int*   cnt3  = (int*)alloc((size_t)3 * N * 4);      // histogram, then cursor
    int*   rp3   = (int*)alloc((size_t)3 * (N + 1) * 4);
    int2*  adj3  = (int2*)alloc((size_t)3 * E * 8);

    // ---- CSR build (topology fixed; reused by 3 layers each) ----
    hipMemsetAsync(cnt3, 0, (size_t)3 * N * 4, stream);
    hist_all<<<(3 * E + 255) / 256, 256, 0, stream>>>(inter_idx, uvt_idx, tuv_idx, E, cnt3, N);
    scan_all<<<3, 1024, 0, stream>>>(cnt3, rp3, N);
    init_cursor<<<(3 * N + 255) / 256, 256, 0, stream>>>(rp3, cnt3, N);  // cnt3 becomes cursor
    scatter_all<<<(3 * E + 255) / 256, 256, 0, stream>>>(inter_idx, uvt_idx, tuv_idx,
                                                         edge_attr, E, cnt3, adj3, N);

    hipMemsetAsync(poolsum, 0, (size_t)B * 288 * 4, stream);
    hipMemsetAsync(bstart, 0, (size_t)B * 4, stream);
    hipMemsetAsync(bend, 0, (size_t)B * 4, stream);
    colsum_kernel<<<1, 128, 0, stream>>>(cWe, ub);
    bounds_kernel<<<(N + 255) / 256, 256, 0, stream>>>(batch, bstart, bend, N);

    float* xcur = nullptr;
    float* xnext = xa;
    for (int i = 0; i < 9; ++i) {
        int r = i % 3;
        const float* xsrc; int ssrc; const float* xdst; int sdst;
        if (i == 0)      { xsrc = inter_emb; ssrc = 64; xdst = inter_emb + 32; sdst = 64; }
        else if (r == 0) { xsrc = xcur; ssrc = 32; xdst = xcur;  sdst = 32; }
        else if (r == 1) { xsrc = xcur; ssrc = 32; xdst = uv_emb; sdst = 32; }
        else             { xsrc = uv_emb; ssrc = 32; xdst = xcur; sdst = 32; }
        const float* ul = (r == 0) ? (ub + (i / 3) * 32) : nullptr;

        qkvs_kernel<<<1024, 256, 0, stream>>>(xsrc, ssrc, xdst, sdst,
            cWq + i * 1024, cbq + i * 32, cWk + i * 1024, cbk + i * 32,
            cWv + i * 1024, cbv + i * 32, cWs + i * 1024, cbs + i * 32,
            ul, qb, kv, sb, qdu, N);
        agg_kernel<<<(N + 7) / 8, 256, 0, stream>>>(
            rp3 + (size_t)r * (N + 1), adj3 + (size_t)r * E,
            qb, kv, qdu, ul, sb, xnext, batch, poolsum, i * 32, N, (r == 0) ? 1 : 0);
        xcur = xnext;
        xnext = (xnext == xa) ? xb : xa;
    }

    head_kernel<<<B, 320, 0, stream>>>(poolsum, bstart, bend,
        W1, b1, W2, b2, W3, b3, W4, b4, W5, b5, W6, b6, (float*)d_out);
}

// Round 4
// 750.054 us; speedup vs baseline: 11.1090x; 1.1822x over previous
//
#include <hip/hip_runtime.h>
#include <math.h>

#define RSQRT32 0.17677669529663687f
#define NSLICE 8
#define TILE 2048

// ---------------- CSR build (once per call; 3 relations) ----------------

// Histogram + per-edge rank (order within its dst bucket). rank store is coalesced.
__global__ void hist_rank(const int* __restrict__ e0, const int* __restrict__ e1,
                          const int* __restrict__ e2, int E,
                          int* __restrict__ cnt3, int* __restrict__ rank3, int N) {
    int t = blockIdx.x * blockDim.x + threadIdx.x;
    if (t >= 3 * E) return;
    int r = (t >= E) + (t >= 2 * E);
    int e = t - r * E;
    const int* ei = (r == 0) ? e0 : ((r == 1) ? e1 : e2);
    rank3[t] = atomicAdd(&cnt3[r * N + ei[E + e]], 1);
}

// Coalesced two-level scan of cnt3 -> rp3 (row pointers). 3 small kernels.
__global__ void scan_tiles_sum(const int* __restrict__ cnt3, int* __restrict__ tsum,
                               int N, int G) {
    int blk = blockIdx.x, r = blk / G, g = blk - r * G;
    int base = g * TILE;
    const int* cnt = cnt3 + (size_t)r * N;
    int s = 0;
    for (int i = threadIdx.x; i < TILE; i += 256) {
        int idx = base + i;
        s += (idx < N) ? cnt[idx] : 0;
    }
    __shared__ int wsum[4];
    for (int m = 32; m; m >>= 1) s += __shfl_down(s, m);
    if ((threadIdx.x & 63) == 0) wsum[threadIdx.x >> 6] = s;
    __syncthreads();
    if (threadIdx.x == 0) tsum[blk] = wsum[0] + wsum[1] + wsum[2] + wsum[3];
}

__global__ void scan_offsets(int* __restrict__ tsum, int* __restrict__ rp3, int N, int G) {
    int r = threadIdx.x;
    if (r < 3) {
        int run = 0;
        for (int g = 0; g < G; ++g) { int v = tsum[r * G + g]; tsum[r * G + g] = run; run += v; }
        rp3[(size_t)r * (N + 1) + N] = run;
    }
}

__global__ void scan_write(const int* __restrict__ cnt3, const int* __restrict__ toff,
                           int* __restrict__ rp3, int N, int G) {
    int blk = blockIdx.x, r = blk / G, g = blk - r * G;
    int base = g * TILE;
    const int* cnt = cnt3 + (size_t)r * N;
    int* rp = rp3 + (size_t)r * (N + 1);
    __shared__ int part[256];
    int t = threadIdx.x;
    int v[8]; int s = 0;
    #pragma unroll
    for (int j = 0; j < 8; ++j) {
        int idx = base + t * 8 + j;
        int x = (idx < N) ? cnt[idx] : 0;
        v[j] = s; s += x;
    }
    part[t] = s;
    __syncthreads();
    for (int off = 1; off < 256; off <<= 1) {
        int x = (t >= off) ? part[t - off] : 0;
        __syncthreads();
        part[t] += x;
        __syncthreads();
    }
    int texcl = part[t] - s + toff[blk];
    #pragma unroll
    for (int j = 0; j < 8; ++j) {
        int idx = base + t * 8 + j;
        if (idx < N) rp[idx] = texcl + v[j];
    }
}

// Sliced scatter: slice = blockIdx&7 owns dst range [s*N/8,(s+1)*N/8) -> all its
// adj writes land in a contiguous ~1.5MB region (stays dense in one XCD L2).
// No atomics: pos = rp[d] + rank[e].
__global__ void scatter_sliced(const int* __restrict__ e0, const int* __restrict__ e1,
                               const int* __restrict__ e2, const float* __restrict__ ea,
                               const int* __restrict__ rank3, const int* __restrict__ rp3,
                               int2* __restrict__ adj3, int E, int N) {
    int slice = blockIdx.x & (NSLICE - 1);
    int wb = blockIdx.x >> 3;
    int nwb = gridDim.x >> 3;
    int T = 3 * E;
    int chunk = (T + nwb - 1) / nwb;
    int beg = wb * chunk, end = min(beg + chunk, T);
    int lo = (int)((long long)slice * N / NSLICE);
    int hi = (int)((long long)(slice + 1) * N / NSLICE);
    for (int t = beg + (int)threadIdx.x; t < end; t += blockDim.x) {
        int r = (t >= E) + (t >= 2 * E);
        int e = t - r * E;
        const int* ei = (r == 0) ? e0 : ((r == 1) ? e1 : e2);
        int d = ei[E + e];
        if (d < lo || d >= hi) continue;
        int pos = rp3[(size_t)r * (N + 1) + d] + rank3[t];
        int2 v;
        v.x = ei[e];
        v.y = (r == 0) ? __float_as_int(ea[e]) : 0;
        adj3[(size_t)r * E + pos] = v;
    }
}

// ---------------- misc small kernels ----------------

__global__ void colsum_kernel(const float* __restrict__ We, float* __restrict__ u) {
    int t = threadIdx.x;
    if (t < 96) {
        int w = t >> 5, j = t & 31;
        const float* W = We + w * 1024;
        float s = 0.f;
        #pragma unroll
        for (int kk = 0; kk < 32; ++kk) s += W[kk * 32 + j];
        u[t] = s;
    }
}

// batch is sorted: graph sizes are run lengths -> plain unique stores, no atomics.
__global__ void bounds_kernel(const int* __restrict__ batch, int* __restrict__ bstart,
                              int* __restrict__ bend, int N) {
    int t = blockIdx.x * blockDim.x + threadIdx.x;
    if (t >= N) return;
    int b = batch[t];
    if (t == 0 || batch[t - 1] != b) bstart[b] = t;
    if (t == N - 1 || batch[t + 1] != b) bend[b] = t + 1;
}

// ---------------- per-layer: fused q,k,v,skip GEMMs (+qdotu) ----------------
// lanes 0-31: q (xd) & v (xs) columns; lanes 32-63: k (xs) & skip (xd) columns.
// k,v written per-channel interleaved: kv[n][2c]=k_c, kv[n][2c+1]=v_c (float2 gathers).
__global__ void qkvs_kernel(
    const float* __restrict__ xs, int ssrc,
    const float* __restrict__ xd, int sdst,
    const float* __restrict__ Wq, const float* __restrict__ bq,
    const float* __restrict__ Wk, const float* __restrict__ bk,
    const float* __restrict__ Wv, const float* __restrict__ bv,
    const float* __restrict__ Ws, const float* __restrict__ bs,
    const float* __restrict__ u,      // nullptr for non-edge layers
    float* __restrict__ qb, float* __restrict__ kv,
    float* __restrict__ sb, float* __restrict__ qdu, int N)
{
    int lane = threadIdx.x & 63;
    int wid  = __builtin_amdgcn_readfirstlane((int)(threadIdx.x >> 6));
    int wpb  = blockDim.x >> 6;
    int gw   = blockIdx.x * wpb + wid;
    int nw   = gridDim.x * wpb;
    int j    = lane & 31;
    bool lower = lane < 32;

    const float* W1 = lower ? Wq : Wk;
    const float* W2 = lower ? Wv : Ws;
    float rw1[32], rw2[32];
    #pragma unroll
    for (int kk = 0; kk < 32; ++kk) {
        rw1[kk] = W1[kk * 32 + j];
        rw2[kk] = W2[kk * 32 + j];
    }
    float bias1 = lower ? bq[j] : bk[j];
    float bias2 = lower ? bv[j] : bs[j];
    float uj = (u != nullptr) ? u[j] : 0.f;

    for (int n = gw; n < N; n += nw) {
        const float* xdr = xd + (size_t)n * sdst;  // wave-uniform -> scalar loads
        const float* xsr = xs + (size_t)n * ssrc;
        float acc1 = bias1, acc2 = bias2;
        #pragma unroll
        for (int kk = 0; kk < 32; ++kk) {
            float xdv = xdr[kk];
            float xsv = xsr[kk];
            float a  = lower ? xdv : xsv;   // q | k input
            float bb = lower ? xsv : xdv;   // v | skip input
            acc1 = fmaf(a,  rw1[kk], acc1);
            acc2 = fmaf(bb, rw2[kk], acc2);
        }
        if (lower) {
            qb[(size_t)n * 32 + j] = acc1;          // q
            kv[(size_t)n * 64 + 2 * j + 1] = acc2;  // v
        } else {
            kv[(size_t)n * 64 + 2 * j] = acc1;      // k
            sb[(size_t)n * 32 + j] = acc2;          // skip
        }
        if (u != nullptr) {
            float pp = lower ? acc1 * uj : 0.f;
            pp += __shfl_xor(pp, 16);
            pp += __shfl_xor(pp, 8);
            pp += __shfl_xor(pp, 4);
            pp += __shfl_xor(pp, 2);
            pp += __shfl_xor(pp, 1);
            if (lane == 0) qdu[n] = pp * RSQRT32;
        }
    }
}

// ---------------- per-layer: gather-side aggregation, no atomics ----------------
// One FULL wave per destination node; lane-halves process even/odd edge streams
// concurrently (+2-way ILP = 4 edges in flight), cross-half shfl_xor(32) combine.
__global__ void agg_kernel(const int* __restrict__ rp, const int2* __restrict__ adj,
    const float* __restrict__ qb, const float* __restrict__ kv,
    const float* __restrict__ qdu, const float* __restrict__ u,
    const float* __restrict__ skp, float* __restrict__ xout,
    const int* __restrict__ batch, float* __restrict__ poolsum,
    int layer_off, int N, int has_ea)
{
    __shared__ float red[32];
    int t = threadIdx.x;
    int w = t >> 6, lane = t & 63, c = lane & 31, half = lane >> 5;
    int n = blockIdx.x * 4 + w;
    float val = 0.f; int b = 0;
    if (n < N) {
        float qc = qb[(size_t)n * 32 + c];
        float qd = has_ea ? qdu[n] : 0.f;
        float uc = has_ea ? u[c] : 0.f;
        int beg = rp[n], end = rp[n + 1];
        float den0 = 0.f, num0 = 0.f, den1 = 0.f, num1 = 0.f;
        int i = beg + half;
        for (; i + 2 < end; i += 4) {
            int2 sv0 = adj[i], sv1 = adj[i + 2];
            float2 kv0 = ((const float2*)(kv + (size_t)sv0.x * 64))[c];
            float2 kv1 = ((const float2*)(kv + (size_t)sv1.x * 64))[c];
            float d0 = qc * kv0.x, d1 = qc * kv1.x;
            d0 += __shfl_xor(d0, 16); d1 += __shfl_xor(d1, 16);
            d0 += __shfl_xor(d0, 8);  d1 += __shfl_xor(d1, 8);
            d0 += __shfl_xor(d0, 4);  d1 += __shfl_xor(d1, 4);
            d0 += __shfl_xor(d0, 2);  d1 += __shfl_xor(d1, 2);
            d0 += __shfl_xor(d0, 1);  d1 += __shfl_xor(d1, 1);
            float ae0 = has_ea ? __int_as_float(sv0.y) : 0.f;
            float ae1 = has_ea ? __int_as_float(sv1.y) : 0.f;
            // softmax is shift-invariant; logits O(+-7) so direct exp is safe
            float ex0 = __expf(fmaf(ae0, qd, d0 * RSQRT32));
            float ex1 = __expf(fmaf(ae1, qd, d1 * RSQRT32));
            den0 += ex0;  den1 += ex1;
            num0 = fmaf(fmaf(ae0, uc, kv0.y), ex0, num0);
            num1 = fmaf(fmaf(ae1, uc, kv1.y), ex1, num1);
        }
        for (; i < end; i += 2) {
            int2 sv = adj[i];
            float2 kvc = ((const float2*)(kv + (size_t)sv.x * 64))[c];
            float d0 = qc * kvc.x;
            d0 += __shfl_xor(d0, 16);
            d0 += __shfl_xor(d0, 8);
            d0 += __shfl_xor(d0, 4);
            d0 += __shfl_xor(d0, 2);
            d0 += __shfl_xor(d0, 1);
            float ae = has_ea ? __int_as_float(sv.y) : 0.f;
            float ex = __expf(fmaf(ae, qd, d0 * RSQRT32));
            den0 += ex;
            num0 = fmaf(fmaf(ae, uc, kvc.y), ex, num0);
        }
        float den = den0 + den1, num = num0 + num1;
        den += __shfl_xor(den, 32);   // combine even/odd halves
        num += __shfl_xor(num, 32);
        val = tanhf(num / (den + 1e-16f) + skp[(size_t)n * 32 + c]);
        if (half == 0) xout[(size_t)n * 32 + c] = val;
        b = batch[n];
    }
    // mean-pool accumulation (batch is sorted: blocks are usually batch-uniform)
    int n0 = blockIdx.x * 4;
    if (n0 >= N) return;
    int nlast = min(n0 + 3, N - 1);
    bool uniform = (batch[n0] == batch[nlast]);
    if (t < 32) red[t] = 0.f;
    __syncthreads();
    if (uniform) {
        if (n < N && half == 0) atomicAdd(&red[c], val);
        __syncthreads();
        if (t < 32) atomicAdd(&poolsum[(size_t)batch[n0] * 288 + layer_off + t], red[t]);
    } else {
        if (n < N && half == 0) atomicAdd(&poolsum[(size_t)b * 288 + layer_off + c], val);
    }
}

// ---------------- head ----------------

__device__ __forceinline__ void gemv_step(const float* __restrict__ W, const float* __restrict__ bias,
    const float* sin_, float* sout, int K, int M, int t, bool do_relu) {
    if (t < M) {
        float acc = bias[t];
        for (int kk = 0; kk < K; ++kk) acc = fmaf(sin_[kk], W[kk * M + t], acc);
        sout[t] = do_relu ? fmaxf(acc, 0.f) : acc;
    }
    __syncthreads();
}

// One block per graph. (mean-pool commutes with W1: mean(s@W1+b1) = mean(s)@W1+b1)
__global__ void head_kernel(const float* __restrict__ poolsum,
    const int* __restrict__ bstart, const int* __restrict__ bend,
    const float* __restrict__ W1, const float* __restrict__ b1,
    const float* __restrict__ W2, const float* __restrict__ b2,
    const float* __restrict__ W3, const float* __restrict__ b3,
    const float* __restrict__ W4, const float* __restrict__ b4,
    const float* __restrict__ W5, const float* __restrict__ b5,
    const float* __restrict__ W6, const float* __restrict__ b6,
    float* __restrict__ out)
{
    __shared__ float ha[288], hb[288];
    __shared__ float lse;
    int b = blockIdx.x, t = threadIdx.x;
    float invc = 1.f / fmaxf((float)(bend[b] - bstart[b]), 1.f);
    if (t < 288) ha[t] = poolsum[(size_t)b * 288 + t] * invc;
    __syncthreads();
    gemv_step(W1, b1, ha, hb, 288, 288, t, false);
    gemv_step(W2, b2, hb, ha, 288, 144, t, true);
    gemv_step(W3, b3, ha, hb, 144, 144, t, false);
    gemv_step(W4, b4, hb, ha, 144, 72,  t, false);
    gemv_step(W5, b5, ha, hb, 72,  72,  t, false);
    gemv_step(W6, b6, hb, ha, 72,  10,  t, false);
    if (t == 0) {
        float m = ha[0];
        for (int i = 1; i < 10; ++i) m = fmaxf(m, ha[i]);
        float ssum = 0.f;
        for (int i = 0; i < 10; ++i) ssum += __expf(ha[i] - m);
        lse = m + logf(ssum);
    }
    __syncthreads();
    if (t < 10) out[b * 10 + t] = ha[t] - lse;
}

// ---------------- launch ----------------

extern "C" void kernel_launch(void* const* d_in, const int* in_sizes, int n_in,
                              void* d_out, int out_size, void* d_ws, size_t ws_size,
                              hipStream_t stream)
{
    const float* inter_emb = (const float*)d_in[0];
    const float* edge_attr = (const float*)d_in[1];
    const float* uv_emb    = (const float*)d_in[2];
    const int* inter_idx = (const int*)d_in[3];
    const int* uvt_idx   = (const int*)d_in[4];
    const int* tuv_idx   = (const int*)d_in[5];
    const int* batch     = (const int*)d_in[6];
    const float* cWq = (const float*)d_in[7];  const float* cbq = (const float*)d_in[8];
    const float* cWk = (const float*)d_in[9];  const float* cbk = (const float*)d_in[10];
    const float* cWv = (const float*)d_in[11]; const float* cbv = (const float*)d_in[12];
    const float* cWs = (const float*)d_in[13]; const float* cbs = (const float*)d_in[14];
    const float* cWe = (const float*)d_in[15];
    const float* W1 = (const float*)d_in[16]; const float* b1 = (const float*)d_in[17];
    const float* W2 = (const float*)d_in[18]; const float* b2 = (const float*)d_in[19];
    const float* W3 = (const float*)d_in[20]; const float* b3 = (const float*)d_in[21];
    const float* W4 = (const float*)d_in[22]; const float* b4 = (const float*)d_in[23];
    const float* W5 = (const float*)d_in[24]; const float* b5 = (const float*)d_in[25];
    const float* W6 = (const float*)d_in[26]; const float* b6 = (const float*)d_in[27];

    const int N = in_sizes[2] / 32;
    const int E = in_sizes[1];
    const int B = out_size / 10;
    const int G = (N + TILE - 1) / TILE;

    char* p = (char*)d_ws;
    auto alloc = [&](size_t bytes) { char* r = p; p += (bytes + 255) & ~(size_t)255; return r; };
    float* qb    = (float*)alloc((size_t)N * 32 * 4);
    float* kv    = (float*)alloc((size_t)N * 64 * 4);   // per-channel interleaved (k,v) float2
    float* sb    = (float*)alloc((size_t)N * 32 * 4);
    float* qdu   = (float*)alloc((size_t)N * 4);
    float* xa    = (float*)alloc((size_t)N * 32 * 4);
    float* xb    = (float*)alloc((size_t)N * 32 * 4);
    float* ub    = (float*)alloc(96 * 4);
    float* poolsum = (float*)alloc((size_t)B * 288 * 4);
    int*   bstart = (int*)alloc((size_t)B * 4);
    int*   bend   = (int*)alloc((size_t)B * 4);
    int*   cnt3  = (int*)alloc((size_t)3 * N * 4);
    int*   rp3   = (int*)alloc((size_t)3 * (N + 1) * 4);
    int*   rank3 = (int*)alloc((size_t)3 * E * 4);
    int*   tsum  = (int*)alloc((size_t)3 * G * 4);
    int2*  adj3  = (int2*)alloc((size_t)3 * E * 8);

    // ---- CSR build (topology fixed; reused by 3 layers each) ----
    hipMemsetAsync(cnt3, 0, (size_t)3 * N * 4, stream);
    hist_rank<<<(3 * E + 255) / 256, 256, 0, stream>>>(inter_idx, uvt_idx, tuv_idx, E,
                                                       cnt3, rank3, N);
    scan_tiles_sum<<<3 * G, 256, 0, stream>>>(cnt3, tsum, N, G);
    scan_offsets<<<1, 64, 0, stream>>>(tsum, rp3, N, G);
    scan_write<<<3 * G, 256, 0, stream>>>(cnt3, tsum, rp3, N, G);
    scatter_sliced<<<6144, 256, 0, stream>>>(inter_idx, uvt_idx, tuv_idx, edge_attr,
                                             rank3, rp3, adj3, E, N);

    hipMemsetAsync(poolsum, 0, (size_t)B * 288 * 4, stream);
    hipMemsetAsync(bstart, 0, (size_t)B * 4, stream);
    hipMemsetAsync(bend, 0, (size_t)B * 4, stream);
    colsum_kernel<<<1, 128, 0, stream>>>(cWe, ub);
    bounds_kernel<<<(N + 255) / 256, 256, 0, stream>>>(batch, bstart, bend, N);

    float* xcur = nullptr;
    float* xnext = xa;
    for (int i = 0; i < 9; ++i) {
        int r = i % 3;
        const float* xsrc; int ssrc; const float* xdst; int sdst;
        if (i == 0)      { xsrc = inter_emb; ssrc = 64; xdst = inter_emb + 32; sdst = 64; }
        else if (r == 0) { xsrc = xcur; ssrc = 32; xdst = xcur;  sdst = 32; }
        else if (r == 1) { xsrc = xcur; ssrc = 32; xdst = uv_emb; sdst = 32; }
        else             { xsrc = uv_emb; ssrc = 32; xdst = xcur; sdst = 32; }
        const float* ul = (r == 0) ? (ub + (i / 3) * 32) : nullptr;

        qkvs_kernel<<<1024, 256, 0, stream>>>(xsrc, ssrc, xdst, sdst,
            cWq + i * 1024, cbq + i * 32, cWk + i * 1024, cbk + i * 32,
            cWv + i * 1024, cbv + i * 32, cWs + i * 1024, cbs + i * 32,
            ul, qb, kv, sb, qdu, N);
        agg_kernel<<<(N + 3) / 4, 256, 0, stream>>>(
            rp3 + (size_t)r * (N + 1), adj3 + (size_t)r * E,
            qb, kv, qdu, ul, sb, xnext, batch, poolsum, i * 32, N, (r == 0) ? 1 : 0);
        xcur = xnext;
        xnext = (xnext == xa) ? xb : xa;
    }

    head_kernel<<<B, 320, 0, stream>>>(poolsum, bstart, bend,
        W1, b1, W2, b2, W3, b3, W4, b4, W5, b5, W6, b6, (float*)d_out);
}

// Round 5
// 692.833 us; speedup vs baseline: 12.0265x; 1.0826x over previous
//
#include <hip/hip_runtime.h>
#include <math.h>

#define RSQRT32 0.17677669529663687f
#define NS 8          // dst slices (LDS histogram fits: 6336*4 = 25 KB)
#define NC 32         // edge chunks per relation
#define MAXBS 6336    // max bins per slice (N=50000 -> BS=6250)
#define TILE 2048

// ---------------- CSR build: atomic-free counting sort ----------------

// Pass 1: per-(relation, slice, chunk) LDS histogram -> partial counts.
__global__ void hist_lds(const int* __restrict__ e0, const int* __restrict__ e1,
                         const int* __restrict__ e2, int E, int N, int BS, int CH,
                         unsigned int* __restrict__ partial) {
    __shared__ unsigned int h[MAXBS];
    int blk = blockIdx.x;
    int c = blk % NC, s = (blk / NC) % NS, r = blk / (NC * NS);
    int lo = s * BS, hi = min(lo + BS, N), nb = hi - lo;
    for (int i = threadIdx.x; i < nb; i += 256) h[i] = 0;
    __syncthreads();
    const int* ei = (r == 0) ? e0 : ((r == 1) ? e1 : e2);
    int ebeg = c * CH, eend = min(ebeg + CH, E);
    const int* dst = ei + E;
    for (int i = ebeg + (int)threadIdx.x; i < eend; i += 256) {
        int d = dst[i];
        if (d >= lo && d < hi) atomicAdd(&h[d - lo], 1u);
    }
    __syncthreads();
    unsigned int* out = partial + ((size_t)blk) * BS;
    for (int i = threadIdx.x; i < nb; i += 256) out[i] = h[i];
}

// Pass 2: per-bin exclusive scan over chunks (in place) + per-dst totals -> cnt3.
// Thread t = (r, s, bin), bin fastest -> coalesced.
__global__ void chunk_scan(unsigned int* __restrict__ partial, int* __restrict__ cnt3,
                           int N, int BS) {
    int t = blockIdx.x * blockDim.x + threadIdx.x;
    int tot = 3 * NS * BS;
    if (t >= tot) return;
    int r = t / (NS * BS);
    int rem = t - r * NS * BS;
    int s = rem / BS, bin = rem - s * BS;
    int d = s * BS + bin;
    if (d >= N) return;
    size_t base = ((size_t)(r * NS + s) * NC) * BS + bin;
    unsigned int run = 0;
    for (int c = 0; c < NC; ++c) {
        unsigned int v = partial[base + (size_t)c * BS];
        partial[base + (size_t)c * BS] = run;
        run += v;
    }
    cnt3[(size_t)r * N + d] = (int)run;
}

// Coalesced two-level scan of cnt3 -> rp3 (row pointers).
__global__ void scan_tiles_sum(const int* __restrict__ cnt3, int* __restrict__ tsum,
                               int N, int G) {
    int blk = blockIdx.x, r = blk / G, g = blk - r * G;
    int base = g * TILE;
    const int* cnt = cnt3 + (size_t)r * N;
    int s = 0;
    for (int i = threadIdx.x; i < TILE; i += 256) {
        int idx = base + i;
        s += (idx < N) ? cnt[idx] : 0;
    }
    __shared__ int wsum[4];
    for (int m = 32; m; m >>= 1) s += __shfl_down(s, m);
    if ((threadIdx.x & 63) == 0) wsum[threadIdx.x >> 6] = s;
    __syncthreads();
    if (threadIdx.x == 0) tsum[blk] = wsum[0] + wsum[1] + wsum[2] + wsum[3];
}

__global__ void scan_offsets(int* __restrict__ tsum, int* __restrict__ rp3, int N, int G) {
    int r = threadIdx.x;
    if (r < 3) {
        int run = 0;
        for (int g = 0; g < G; ++g) { int v = tsum[r * G + g]; tsum[r * G + g] = run; run += v; }
        rp3[(size_t)r * (N + 1) + N] = run;
    }
}

__global__ void scan_write(const int* __restrict__ cnt3, const int* __restrict__ toff,
                           int* __restrict__ rp3, int N, int G) {
    int blk = blockIdx.x, r = blk / G, g = blk - r * G;
    int base = g * TILE;
    const int* cnt = cnt3 + (size_t)r * N;
    int* rp = rp3 + (size_t)r * (N + 1);
    __shared__ int part[256];
    int t = threadIdx.x;
    int v[8]; int s = 0;
    #pragma unroll
    for (int j = 0; j < 8; ++j) {
        int idx = base + t * 8 + j;
        int x = (idx < N) ? cnt[idx] : 0;
        v[j] = s; s += x;
    }
    part[t] = s;
    __syncthreads();
    for (int off = 1; off < 256; off <<= 1) {
        int x = (t >= off) ? part[t - off] : 0;
        __syncthreads();
        part[t] += x;
        __syncthreads();
    }
    int texcl = part[t] - s + toff[blk];
    #pragma unroll
    for (int j = 0; j < 8; ++j) {
        int idx = base + t * 8 + j;
        if (idx < N) rp[idx] = texcl + v[j];
    }
}

// Pass 3: scatter via LDS cursors (rp + chunk offset); no global atomics.
// adj payload: .x = src node, .y = bitcast(edge_attr) for relation 0 else 0.
__global__ void scatter_cs(const int* __restrict__ e0, const int* __restrict__ e1,
                           const int* __restrict__ e2, const float* __restrict__ ea,
                           const unsigned int* __restrict__ partial,
                           const int* __restrict__ rp3,
                           int2* __restrict__ adj3, int E, int N, int BS, int CH) {
    __shared__ unsigned int cur[MAXBS];
    int blk = blockIdx.x;
    int c = blk % NC, s = (blk / NC) % NS, r = blk / (NC * NS);
    int lo = s * BS, hi = min(lo + BS, N), nb = hi - lo;
    const unsigned int* po = partial + ((size_t)blk) * BS;
    const int* rp = rp3 + (size_t)r * (N + 1);
    for (int i = threadIdx.x; i < nb; i += 256)
        cur[i] = (unsigned int)rp[lo + i] + po[i];
    __syncthreads();
    const int* ei = (r == 0) ? e0 : ((r == 1) ? e1 : e2);
    const int* srcp = ei;
    const int* dstp = ei + E;
    int ebeg = c * CH, eend = min(ebeg + CH, E);
    int2* adj = adj3 + (size_t)r * E;
    for (int i = ebeg + (int)threadIdx.x; i < eend; i += 256) {
        int d = dstp[i];
        if (d < lo || d >= hi) continue;
        unsigned int pos = atomicAdd(&cur[d - lo], 1u);
        int2 v;
        v.x = srcp[i];
        v.y = (r == 0) ? __float_as_int(ea[i]) : 0;
        adj[pos] = v;
    }
}

// ---------------- misc small kernels ----------------

__global__ void colsum_kernel(const float* __restrict__ We, float* __restrict__ u) {
    int t = threadIdx.x;
    if (t < 96) {
        int w = t >> 5, j = t & 31;
        const float* W = We + w * 1024;
        float s = 0.f;
        #pragma unroll
        for (int kk = 0; kk < 32; ++kk) s += W[kk * 32 + j];
        u[t] = s;
    }
}

// batch is sorted: graph sizes are run lengths -> plain unique stores, no atomics.
__global__ void bounds_kernel(const int* __restrict__ batch, int* __restrict__ bstart,
                              int* __restrict__ bend, int N) {
    int t = blockIdx.x * blockDim.x + threadIdx.x;
    if (t >= N) return;
    int b = batch[t];
    if (t == 0 || batch[t - 1] != b) bstart[b] = t;
    if (t == N - 1 || batch[t + 1] != b) bend[b] = t + 1;
}

// ---------------- per-layer: fused q,k,v,skip GEMMs (+qdotu) ----------------
// lanes 0-31: q (xd) & v (xs) columns; lanes 32-63: k (xs) & skip (xd) columns.
// k,v written per-channel interleaved: kv[n][2c]=k_c, kv[n][2c+1]=v_c (float2 gathers).
__global__ void qkvs_kernel(
    const float* __restrict__ xs, int ssrc,
    const float* __restrict__ xd, int sdst,
    const float* __restrict__ Wq, const float* __restrict__ bq,
    const float* __restrict__ Wk, const float* __restrict__ bk,
    const float* __restrict__ Wv, const float* __restrict__ bv,
    const float* __restrict__ Ws, const float* __restrict__ bs,
    const float* __restrict__ u,      // nullptr for non-edge layers
    float* __restrict__ qb, float* __restrict__ kv,
    float* __restrict__ sb, float* __restrict__ qdu, int N)
{
    int lane = threadIdx.x & 63;
    int wid  = __builtin_amdgcn_readfirstlane((int)(threadIdx.x >> 6));
    int wpb  = blockDim.x >> 6;
    int gw   = blockIdx.x * wpb + wid;
    int nw   = gridDim.x * wpb;
    int j    = lane & 31;
    bool lower = lane < 32;

    const float* W1 = lower ? Wq : Wk;
    const float* W2 = lower ? Wv : Ws;
    float rw1[32], rw2[32];
    #pragma unroll
    for (int kk = 0; kk < 32; ++kk) {
        rw1[kk] = W1[kk * 32 + j];
        rw2[kk] = W2[kk * 32 + j];
    }
    float bias1 = lower ? bq[j] : bk[j];
    float bias2 = lower ? bv[j] : bs[j];
    float uj = (u != nullptr) ? u[j] : 0.f;

    for (int n = gw; n < N; n += nw) {
        const float* xdr = xd + (size_t)n * sdst;  // wave-uniform -> scalar loads
        const float* xsr = xs + (size_t)n * ssrc;
        float acc1 = bias1, acc2 = bias2;
        #pragma unroll
        for (int kk = 0; kk < 32; ++kk) {
            float xdv = xdr[kk];
            float xsv = xsr[kk];
            float a  = lower ? xdv : xsv;   // q | k input
            float bb = lower ? xsv : xdv;   // v | skip input
            acc1 = fmaf(a,  rw1[kk], acc1);
            acc2 = fmaf(bb, rw2[kk], acc2);
        }
        if (lower) {
            qb[(size_t)n * 32 + j] = acc1;          // q
            kv[(size_t)n * 64 + 2 * j + 1] = acc2;  // v
        } else {
            kv[(size_t)n * 64 + 2 * j] = acc1;      // k
            sb[(size_t)n * 32 + j] = acc2;          // skip
        }
        if (u != nullptr) {
            float pp = lower ? acc1 * uj : 0.f;
            pp += __shfl_xor(pp, 16);
            pp += __shfl_xor(pp, 8);
            pp += __shfl_xor(pp, 4);
            pp += __shfl_xor(pp, 2);
            pp += __shfl_xor(pp, 1);
            if (lane == 0) qdu[n] = pp * RSQRT32;
        }
    }
}

// ---------------- per-layer: gather-side aggregation (pure, no LDS/atomics) ----
// One FULL wave per destination node; lane-halves process even/odd edge streams
// concurrently (+2-way ILP = 4 edges in flight), cross-half shfl_xor(32) combine.
__global__ void agg_kernel(const int* __restrict__ rp, const int2* __restrict__ adj,
    const float* __restrict__ qb, const float* __restrict__ kv,
    const float* __restrict__ qdu, const float* __restrict__ u,
    const float* __restrict__ skp, float* __restrict__ xout,
    int N, int has_ea)
{
    int t = threadIdx.x;
    int w = t >> 6, lane = t & 63, c = lane & 31, half = lane >> 5;
    int n = blockIdx.x * 4 + w;
    if (n >= N) return;
    float qc = qb[(size_t)n * 32 + c];
    float qd = has_ea ? qdu[n] : 0.f;
    float uc = has_ea ? u[c] : 0.f;
    int beg = rp[n], end = rp[n + 1];
    float den0 = 0.f, num0 = 0.f, den1 = 0.f, num1 = 0.f;
    int i = beg + half;
    for (; i + 2 < end; i += 4) {
        int2 sv0 = adj[i], sv1 = adj[i + 2];
        float2 kv0 = ((const float2*)(kv + (size_t)sv0.x * 64))[c];
        float2 kv1 = ((const float2*)(kv + (size_t)sv1.x * 64))[c];
        float d0 = qc * kv0.x, d1 = qc * kv1.x;
        d0 += __shfl_xor(d0, 16); d1 += __shfl_xor(d1, 16);
        d0 += __shfl_xor(d0, 8);  d1 += __shfl_xor(d1, 8);
        d0 += __shfl_xor(d0, 4);  d1 += __shfl_xor(d1, 4);
        d0 += __shfl_xor(d0, 2);  d1 += __shfl_xor(d1, 2);
        d0 += __shfl_xor(d0, 1);  d1 += __shfl_xor(d1, 1);
        float ae0 = has_ea ? __int_as_float(sv0.y) : 0.f;
        float ae1 = has_ea ? __int_as_float(sv1.y) : 0.f;
        // softmax is shift-invariant; logits O(+-7) so direct exp is safe
        float ex0 = __expf(fmaf(ae0, qd, d0 * RSQRT32));
        float ex1 = __expf(fmaf(ae1, qd, d1 * RSQRT32));
        den0 += ex0;  den1 += ex1;
        num0 = fmaf(fmaf(ae0, uc, kv0.y), ex0, num0);
        num1 = fmaf(fmaf(ae1, uc, kv1.y), ex1, num1);
    }
    for (; i < end; i += 2) {
        int2 sv = adj[i];
        float2 kvc = ((const float2*)(kv + (size_t)sv.x * 64))[c];
        float d0 = qc * kvc.x;
        d0 += __shfl_xor(d0, 16);
        d0 += __shfl_xor(d0, 8);
        d0 += __shfl_xor(d0, 4);
        d0 += __shfl_xor(d0, 2);
        d0 += __shfl_xor(d0, 1);
        float ae = has_ea ? __int_as_float(sv.y) : 0.f;
        float ex = __expf(fmaf(ae, qd, d0 * RSQRT32));
        den0 += ex;
        num0 = fmaf(fmaf(ae, uc, kvc.y), ex, num0);
    }
    float den = den0 + den1, num = num0 + num1;
    den += __shfl_xor(den, 32);   // combine even/odd halves
    num += __shfl_xor(num, 32);
    float val = tanhf(num / (den + 1e-16f) + skp[(size_t)n * 32 + c]);
    if (half == 0) xout[(size_t)n * 32 + c] = val;
}

// ---------------- per-layer pooling (coalesced; 1 atomic row per block) --------
// Block = (graph b, 1/8 sub-range). Thread t: col t&31, rows strided by 8.
__global__ void pool_kernel(const float* __restrict__ x,
                            const int* __restrict__ bstart, const int* __restrict__ bend,
                            float* __restrict__ poolsum, int layer_off) {
    __shared__ float red[256];
    int b = blockIdx.x >> 3, sub = blockIdx.x & 7;
    int s0 = bstart[b], s1 = bend[b];
    int cnt = s1 - s0;
    int n0 = s0 + (int)((long long)cnt * sub / 8);
    int n1 = s0 + (int)((long long)cnt * (sub + 1) / 8);
    int t = threadIdx.x, col = t & 31, g = t >> 5;
    float acc = 0.f;
    for (int n = n0 + g; n < n1; n += 8)
        acc += x[(size_t)n * 32 + col];
    red[t] = acc;
    __syncthreads();
    if (t < 32) {
        float s = red[t];
        #pragma unroll
        for (int k = 1; k < 8; ++k) s += red[t + 32 * k];
        atomicAdd(&poolsum[(size_t)b * 288 + layer_off + t], s);
    }
}

// ---------------- head ----------------

__device__ __forceinline__ void gemv_step(const float* __restrict__ W, const float* __restrict__ bias,
    const float* sin_, float* sout, int K, int M, int t, bool do_relu) {
    if (t < M) {
        float acc = bias[t];
        for (int kk = 0; kk < K; ++kk) acc = fmaf(sin_[kk], W[kk * M + t], acc);
        sout[t] = do_relu ? fmaxf(acc, 0.f) : acc;
    }
    __syncthreads();
}

// One block per graph. (mean-pool commutes with W1: mean(s@W1+b1) = mean(s)@W1+b1)
__global__ void head_kernel(const float* __restrict__ poolsum,
    const int* __restrict__ bstart, const int* __restrict__ bend,
    const float* __restrict__ W1, const float* __restrict__ b1,
    const float* __restrict__ W2, const float* __restrict__ b2,
    const float* __restrict__ W3, const float* __restrict__ b3,
    const float* __restrict__ W4, const float* __restrict__ b4,
    const float* __restrict__ W5, const float* __restrict__ b5,
    const float* __restrict__ W6, const float* __restrict__ b6,
    float* __restrict__ out)
{
    __shared__ float ha[288], hb[288];
    __shared__ float lse;
    int b = blockIdx.x, t = threadIdx.x;
    float invc = 1.f / fmaxf((float)(bend[b] - bstart[b]), 1.f);
    if (t < 288) ha[t] = poolsum[(size_t)b * 288 + t] * invc;
    __syncthreads();
    gemv_step(W1, b1, ha, hb, 288, 288, t, false);
    gemv_step(W2, b2, hb, ha, 288, 144, t, true);
    gemv_step(W3, b3, ha, hb, 144, 144, t, false);
    gemv_step(W4, b4, hb, ha, 144, 72,  t, false);
    gemv_step(W5, b5, ha, hb, 72,  72,  t, false);
    gemv_step(W6, b6, hb, ha, 72,  10,  t, false);
    if (t == 0) {
        float m = ha[0];
        for (int i = 1; i < 10; ++i) m = fmaxf(m, ha[i]);
        float ssum = 0.f;
        for (int i = 0; i < 10; ++i) ssum += __expf(ha[i] - m);
        lse = m + logf(ssum);
    }
    __syncthreads();
    if (t < 10) out[b * 10 + t] = ha[t] - lse;
}

// ---------------- launch ----------------

extern "C" void kernel_launch(void* const* d_in, const int* in_sizes, int n_in,
                              void* d_out, int out_size, void* d_ws, size_t ws_size,
                              hipStream_t stream)
{
    const float* inter_emb = (const float*)d_in[0];
    const float* edge_attr = (const float*)d_in[1];
    const float* uv_emb    = (const float*)d_in[2];
    const int* inter_idx = (const int*)d_in[3];
    const int* uvt_idx   = (const int*)d_in[4];
    const int* tuv_idx   = (const int*)d_in[5];
    const int* batch     = (const int*)d_in[6];
    const float* cWq = (const float*)d_in[7];  const float* cbq = (const float*)d_in[8];
    const float* cWk = (const float*)d_in[9];  const float* cbk = (const float*)d_in[10];
    const float* cWv = (const float*)d_in[11]; const float* cbv = (const float*)d_in[12];
    const float* cWs = (const float*)d_in[13]; const float* cbs = (const float*)d_in[14];
    const float* cWe = (const float*)d_in[15];
    const float* W1 = (const float*)d_in[16]; const float* b1 = (const float*)d_in[17];
    const float* W2 = (const float*)d_in[18]; const float* b2 = (const float*)d_in[19];
    const float* W3 = (const float*)d_in[20]; const float* b3 = (const float*)d_in[21];
    const float* W4 = (const float*)d_in[22]; const float* b4 = (const float*)d_in[23];
    const float* W5 = (const float*)d_in[24]; const float* b5 = (const float*)d_in[25];
    const float* W6 = (const float*)d_in[26]; const float* b6 = (const float*)d_in[27];

    const int N = in_sizes[2] / 32;
    const int E = in_sizes[1];
    const int B = out_size / 10;
    const int G = (N + TILE - 1) / TILE;
    const int BS = (N + NS - 1) / NS;      // bins per slice (<= MAXBS)
    const int CH = (E + NC - 1) / NC;      // edges per chunk

    char* p = (char*)d_ws;
    auto alloc = [&](size_t bytes) { char* r = p; p += (bytes + 255) & ~(size_t)255; return r; };
    float* qb    = (float*)alloc((size_t)N * 32 * 4);
    float* kv    = (float*)alloc((size_t)N * 64 * 4);   // per-channel interleaved (k,v) float2
    float* sb    = (float*)alloc((size_t)N * 32 * 4);
    float* qdu   = (float*)alloc((size_t)N * 4);
    float* xa    = (float*)alloc((size_t)N * 32 * 4);
    float* xb    = (float*)alloc((size_t)N * 32 * 4);
    float* ub    = (float*)alloc(96 * 4);
    float* poolsum = (float*)alloc((size_t)B * 288 * 4);
    int*   bstart = (int*)alloc((size_t)B * 4);
    int*   bend   = (int*)alloc((size_t)B * 4);
    int*   cnt3  = (int*)alloc((size_t)3 * N * 4);
    int*   rp3   = (int*)alloc((size_t)3 * (N + 1) * 4);
    int*   tsum  = (int*)alloc((size_t)3 * G * 4);
    unsigned int* partial = (unsigned int*)alloc((size_t)3 * NS * NC * BS * 4);
    int2*  adj3  = (int2*)alloc((size_t)3 * E * 8);

    // ---- CSR build: counting sort, no global atomics ----
    hist_lds<<<3 * NS * NC, 256, 0, stream>>>(inter_idx, uvt_idx, tuv_idx, E, N, BS, CH, partial);
    chunk_scan<<<(3 * NS * BS + 255) / 256, 256, 0, stream>>>(partial, cnt3, N, BS);
    scan_tiles_sum<<<3 * G, 256, 0, stream>>>(cnt3, tsum, N, G);
    scan_offsets<<<1, 64, 0, stream>>>(tsum, rp3, N, G);
    scan_write<<<3 * G, 256, 0, stream>>>(cnt3, tsum, rp3, N, G);
    scatter_cs<<<3 * NS * NC, 256, 0, stream>>>(inter_idx, uvt_idx, tuv_idx, edge_attr,
                                                partial, rp3, adj3, E, N, BS, CH);

    hipMemsetAsync(poolsum, 0, (size_t)B * 288 * 4, stream);
    hipMemsetAsync(bstart, 0, (size_t)B * 4, stream);
    hipMemsetAsync(bend, 0, (size_t)B * 4, stream);
    colsum_kernel<<<1, 128, 0, stream>>>(cWe, ub);
    bounds_kernel<<<(N + 255) / 256, 256, 0, stream>>>(batch, bstart, bend, N);

    float* xcur = nullptr;
    float* xnext = xa;
    for (int i = 0; i < 9; ++i) {
        int r = i % 3;
        const float* xsrc; int ssrc; const float* xdst; int sdst;
        if (i == 0)      { xsrc = inter_emb; ssrc = 64; xdst = inter_emb + 32; sdst = 64; }
        else if (r == 0) { xsrc = xcur; ssrc = 32; xdst = xcur;  sdst = 32; }
        else if (r == 1) { xsrc = xcur; ssrc = 32; xdst = uv_emb; sdst = 32; }
        else             { xsrc = uv_emb; ssrc = 32; xdst = xcur; sdst = 32; }
        const float* ul = (r == 0) ? (ub + (i / 3) * 32) : nullptr;

        qkvs_kernel<<<1024, 256, 0, stream>>>(xsrc, ssrc, xdst, sdst,
            cWq + i * 1024, cbq + i * 32, cWk + i * 1024, cbk + i * 32,
            cWv + i * 1024, cbv + i * 32, cWs + i * 1024, cbs + i * 32,
            ul, qb, kv, sb, qdu, N);
        agg_kernel<<<(N + 3) / 4, 256, 0, stream>>>(
            rp3 + (size_t)r * (N + 1), adj3 + (size_t)r * E,
            qb, kv, qdu, ul, sb, xnext, N, (r == 0) ? 1 : 0);
        pool_kernel<<<B * 8, 256, 0, stream>>>(xnext, bstart, bend, poolsum, i * 32);
        xcur = xnext;
        xnext = (xnext == xa) ? xb : xa;
    }

    head_kernel<<<B, 320, 0, stream>>>(poolsum, bstart, bend,
        W1, b1, W2, b2, W3, b3, W4, b4, W5, b5, W6, b6, (float*)d_out);
}

// Round 6
// 623.747 us; speedup vs baseline: 13.3586x; 1.1108x over previous
//
#include <hip/hip_runtime.h>
#include <hip/hip_fp16.h>
#include <math.h>

#define RSQRT32 0.17677669529663687f
#define NS 8          // dst slices (LDS histogram fits: 6336*4 = 25 KB)
#define NC 32         // edge chunks per relation
#define MAXBS 6336    // max bins per slice (N=50000 -> BS=6250)
#define TILE 2048

// ---------------- CSR build: atomic-free counting sort ----------------

// Pass 1: per-(relation, slice, chunk) LDS histogram -> partial counts.
__global__ void hist_lds(const int* __restrict__ e0, const int* __restrict__ e1,
                         const int* __restrict__ e2, int E, int N, int BS, int CH,
                         unsigned int* __restrict__ partial) {
    __shared__ unsigned int h[MAXBS];
    int blk = blockIdx.x;
    int c = blk % NC, s = (blk / NC) % NS, r = blk / (NC * NS);
    int lo = s * BS, hi = min(lo + BS, N), nb = hi - lo;
    for (int i = threadIdx.x; i < nb; i += 256) h[i] = 0;
    __syncthreads();
    const int* ei = (r == 0) ? e0 : ((r == 1) ? e1 : e2);
    int ebeg = c * CH, eend = min(ebeg + CH, E);
    const int* dst = ei + E;
    for (int i = ebeg + (int)threadIdx.x; i < eend; i += 256) {
        int d = dst[i];
        if (d >= lo && d < hi) atomicAdd(&h[d - lo], 1u);
    }
    __syncthreads();
    unsigned int* out = partial + ((size_t)blk) * BS;
    for (int i = threadIdx.x; i < nb; i += 256) out[i] = h[i];
}

// Pass 2: per-bin exclusive scan over chunks (in place) + per-dst totals -> cnt3.
__global__ void chunk_scan(unsigned int* __restrict__ partial, int* __restrict__ cnt3,
                           int N, int BS) {
    int t = blockIdx.x * blockDim.x + threadIdx.x;
    int tot = 3 * NS * BS;
    if (t >= tot) return;
    int r = t / (NS * BS);
    int rem = t - r * NS * BS;
    int s = rem / BS, bin = rem - s * BS;
    int d = s * BS + bin;
    if (d >= N) return;
    size_t base = ((size_t)(r * NS + s) * NC) * BS + bin;
    unsigned int run = 0;
    for (int c = 0; c < NC; ++c) {
        unsigned int v = partial[base + (size_t)c * BS];
        partial[base + (size_t)c * BS] = run;
        run += v;
    }
    cnt3[(size_t)r * N + d] = (int)run;
}

// Coalesced two-level scan of cnt3 -> rp3 (row pointers).
__global__ void scan_tiles_sum(const int* __restrict__ cnt3, int* __restrict__ tsum,
                               int N, int G) {
    int blk = blockIdx.x, r = blk / G, g = blk - r * G;
    int base = g * TILE;
    const int* cnt = cnt3 + (size_t)r * N;
    int s = 0;
    for (int i = threadIdx.x; i < TILE; i += 256) {
        int idx = base + i;
        s += (idx < N) ? cnt[idx] : 0;
    }
    __shared__ int wsum[4];
    for (int m = 32; m; m >>= 1) s += __shfl_down(s, m);
    if ((threadIdx.x & 63) == 0) wsum[threadIdx.x >> 6] = s;
    __syncthreads();
    if (threadIdx.x == 0) tsum[blk] = wsum[0] + wsum[1] + wsum[2] + wsum[3];
}

__global__ void scan_offsets(int* __restrict__ tsum, int* __restrict__ rp3, int N, int G) {
    int r = threadIdx.x;
    if (r < 3) {
        int run = 0;
        for (int g = 0; g < G; ++g) { int v = tsum[r * G + g]; tsum[r * G + g] = run; run += v; }
        rp3[(size_t)r * (N + 1) + N] = run;
    }
}

__global__ void scan_write(const int* __restrict__ cnt3, const int* __restrict__ toff,
                           int* __restrict__ rp3, int N, int G) {
    int blk = blockIdx.x, r = blk / G, g = blk - r * G;
    int base = g * TILE;
    const int* cnt = cnt3 + (size_t)r * N;
    int* rp = rp3 + (size_t)r * (N + 1);
    __shared__ int part[256];
    int t = threadIdx.x;
    int v[8]; int s = 0;
    #pragma unroll
    for (int j = 0; j < 8; ++j) {
        int idx = base + t * 8 + j;
        int x = (idx < N) ? cnt[idx] : 0;
        v[j] = s; s += x;
    }
    part[t] = s;
    __syncthreads();
    for (int off = 1; off < 256; off <<= 1) {
        int x = (t >= off) ? part[t - off] : 0;
        __syncthreads();
        part[t] += x;
        __syncthreads();
    }
    int texcl = part[t] - s + toff[blk];
    #pragma unroll
    for (int j = 0; j < 8; ++j) {
        int idx = base + t * 8 + j;
        if (idx < N) rp[idx] = texcl + v[j];
    }
}

// Pass 3: scatter via LDS cursors; no global atomics.
// r==0 -> adj0 (int2: src, edge_attr bits); r in {1,2} -> adj12 (int src only).
__global__ void scatter_cs(const int* __restrict__ e0, const int* __restrict__ e1,
                           const int* __restrict__ e2, const float* __restrict__ ea,
                           const unsigned int* __restrict__ partial,
                           const int* __restrict__ rp3,
                           int2* __restrict__ adj0, int* __restrict__ adj12,
                           int E, int N, int BS, int CH) {
    __shared__ unsigned int cur[MAXBS];
    int blk = blockIdx.x;
    int c = blk % NC, s = (blk / NC) % NS, r = blk / (NC * NS);
    int lo = s * BS, hi = min(lo + BS, N), nb = hi - lo;
    const unsigned int* po = partial + ((size_t)blk) * BS;
    const int* rp = rp3 + (size_t)r * (N + 1);
    for (int i = threadIdx.x; i < nb; i += 256)
        cur[i] = (unsigned int)rp[lo + i] + po[i];
    __syncthreads();
    const int* ei = (r == 0) ? e0 : ((r == 1) ? e1 : e2);
    const int* srcp = ei;
    const int* dstp = ei + E;
    int ebeg = c * CH, eend = min(ebeg + CH, E);
    if (r == 0) {
        for (int i = ebeg + (int)threadIdx.x; i < eend; i += 256) {
            int d = dstp[i];
            if (d < lo || d >= hi) continue;
            unsigned int pos = atomicAdd(&cur[d - lo], 1u);
            int2 v; v.x = srcp[i]; v.y = __float_as_int(ea[i]);
            adj0[pos] = v;
        }
    } else {
        int* adj = adj12 + (size_t)(r - 1) * E;
        for (int i = ebeg + (int)threadIdx.x; i < eend; i += 256) {
            int d = dstp[i];
            if (d < lo || d >= hi) continue;
            unsigned int pos = atomicAdd(&cur[d - lo], 1u);
            adj[pos] = srcp[i];
        }
    }
}

// ---------------- misc small kernels ----------------

__global__ void colsum_kernel(const float* __restrict__ We, float* __restrict__ u) {
    int t = threadIdx.x;
    if (t < 96) {
        int w = t >> 5, j = t & 31;
        const float* W = We + w * 1024;
        float s = 0.f;
        #pragma unroll
        for (int kk = 0; kk < 32; ++kk) s += W[kk * 32 + j];
        u[t] = s;
    }
}

// batch is sorted: graph bounds are run boundaries -> plain unique stores.
__global__ void bounds_kernel(const int* __restrict__ batch, int* __restrict__ bstart,
                              int* __restrict__ bend, int N) {
    int t = blockIdx.x * blockDim.x + threadIdx.x;
    if (t >= N) return;
    int b = batch[t];
    if (t == 0 || batch[t - 1] != b) bstart[b] = t;
    if (t == N - 1 || batch[t + 1] != b) bend[b] = t + 1;
}

// ---------------- per-layer: fused q,k,v,skip GEMMs (+qdotu) ----------------
// lanes 0-31: q (xd) & v (xs) columns; lanes 32-63: k (xs) & skip (xd) columns.
// kv packed fp16: kv[n][c] = half2(k_c, v_c) -> 128B row, 4B per channel.
__global__ void qkvs_kernel(
    const float* __restrict__ xs, int ssrc,
    const float* __restrict__ xd, int sdst,
    const float* __restrict__ Wq, const float* __restrict__ bq,
    const float* __restrict__ Wk, const float* __restrict__ bk,
    const float* __restrict__ Wv, const float* __restrict__ bv,
    const float* __restrict__ Ws, const float* __restrict__ bs,
    const float* __restrict__ u,      // nullptr for non-edge layers
    float* __restrict__ qb, __half2* __restrict__ kv,
    float* __restrict__ sb, float* __restrict__ qdu, int N)
{
    int lane = threadIdx.x & 63;
    int wid  = __builtin_amdgcn_readfirstlane((int)(threadIdx.x >> 6));
    int wpb  = blockDim.x >> 6;
    int gw   = blockIdx.x * wpb + wid;
    int nw   = gridDim.x * wpb;
    int j    = lane & 31;
    bool lower = lane < 32;

    const float* W1 = lower ? Wq : Wk;
    const float* W2 = lower ? Wv : Ws;
    float rw1[32], rw2[32];
    #pragma unroll
    for (int kk = 0; kk < 32; ++kk) {
        rw1[kk] = W1[kk * 32 + j];
        rw2[kk] = W2[kk * 32 + j];
    }
    float bias1 = lower ? bq[j] : bk[j];
    float bias2 = lower ? bv[j] : bs[j];
    float uj = (u != nullptr) ? u[j] : 0.f;

    for (int n = gw; n < N; n += nw) {
        const float* xdr = xd + (size_t)n * sdst;  // wave-uniform -> scalar loads
        const float* xsr = xs + (size_t)n * ssrc;
        float acc1 = bias1, acc2 = bias2;
        #pragma unroll
        for (int kk = 0; kk < 32; ++kk) {
            float xdv = xdr[kk];
            float xsv = xsr[kk];
            float a  = lower ? xdv : xsv;   // q | k input
            float bb = lower ? xsv : xdv;   // v | skip input
            acc1 = fmaf(a,  rw1[kk], acc1);
            acc2 = fmaf(bb, rw2[kk], acc2);
        }
        float kk_ = __shfl(acc1, j + 32);   // k_j from upper half
        if (lower) {
            qb[(size_t)n * 32 + j] = acc1;                  // q
            kv[(size_t)n * 32 + j] = __floats2half2_rn(kk_, acc2);  // (k, v)
        } else {
            sb[(size_t)n * 32 + j] = acc2;                  // skip
        }
        if (u != nullptr) {
            float pp = lower ? acc1 * uj : 0.f;
            pp += __shfl_xor(pp, 16);
            pp += __shfl_xor(pp, 8);
            pp += __shfl_xor(pp, 4);
            pp += __shfl_xor(pp, 2);
            pp += __shfl_xor(pp, 1);
            if (lane == 0) qdu[n] = pp * RSQRT32;
        }
    }
}

// ---------------- per-layer: gather-side aggregation (pure, no atomics) -------
// One wave per dst node. Lane = (quarter, cp): cp owns channels 2cp,2cp+1.
// 4 quarters x 2-way ILP = 8 edges in flight. 4-step shfl dot per edge.
template<int HAS_EA>
__global__ void agg_kernel(const int* __restrict__ rp, const void* __restrict__ adjv,
    const float* __restrict__ qb, const __half2* __restrict__ kv,
    const float* __restrict__ qdu, const float* __restrict__ u,
    const float* __restrict__ skp, float* __restrict__ xout, int N)
{
    int t = threadIdx.x;
    int w = t >> 6, lane = t & 63;
    int cp = lane & 15, quarter = lane >> 4;
    int n = blockIdx.x * 4 + w;
    if (n >= N) return;
    float2 qc = ((const float2*)(qb + (size_t)n * 32))[cp];
    float qd = HAS_EA ? qdu[n] : 0.f;
    float2 uc = HAS_EA ? ((const float2*)u)[cp] : make_float2(0.f, 0.f);
    int beg = rp[n], end = rp[n + 1];
    float den0 = 0.f, den1 = 0.f;
    float2 num0 = make_float2(0.f, 0.f), num1 = make_float2(0.f, 0.f);
    const int2* adjE = (const int2*)adjv;
    const int*  adjP = (const int*)adjv;
    int i = beg + quarter;
    for (; i + 4 < end; i += 8) {
        int s0, s1; float ae0 = 0.f, ae1 = 0.f;
        if (HAS_EA) {
            int2 a0 = adjE[i], a1 = adjE[i + 4];
            s0 = a0.x; s1 = a1.x;
            ae0 = __int_as_float(a0.y); ae1 = __int_as_float(a1.y);
        } else { s0 = adjP[i]; s1 = adjP[i + 4]; }
        uint2 p0 = ((const uint2*)(kv + (size_t)s0 * 32))[cp];
        uint2 p1 = ((const uint2*)(kv + (size_t)s1 * 32))[cp];
        float2 a00 = __half22float2(*(const __half2*)&p0.x);  // (k,v) ch 2cp
        float2 a01 = __half22float2(*(const __half2*)&p0.y);  // (k,v) ch 2cp+1
        float2 a10 = __half22float2(*(const __half2*)&p1.x);
        float2 a11 = __half22float2(*(const __half2*)&p1.y);
        float d0 = fmaf(qc.x, a00.x, qc.y * a01.x);
        float d1 = fmaf(qc.x, a10.x, qc.y * a11.x);
        d0 += __shfl_xor(d0, 8);  d1 += __shfl_xor(d1, 8);
        d0 += __shfl_xor(d0, 4);  d1 += __shfl_xor(d1, 4);
        d0 += __shfl_xor(d0, 2);  d1 += __shfl_xor(d1, 2);
        d0 += __shfl_xor(d0, 1);  d1 += __shfl_xor(d1, 1);
        // softmax is shift-invariant; logits O(+-7) so direct exp is safe
        float ex0 = __expf(fmaf(ae0, qd, d0 * RSQRT32));
        float ex1 = __expf(fmaf(ae1, qd, d1 * RSQRT32));
        den0 += ex0;  den1 += ex1;
        num0.x = fmaf(fmaf(ae0, uc.x, a00.y), ex0, num0.x);
        num0.y = fmaf(fmaf(ae0, uc.y, a01.y), ex0, num0.y);
        num1.x = fmaf(fmaf(ae1, uc.x, a10.y), ex1, num1.x);
        num1.y = fmaf(fmaf(ae1, uc.y, a11.y), ex1, num1.y);
    }
    for (; i < end; i += 4) {
        int s0; float ae0 = 0.f;
        if (HAS_EA) { int2 a0 = adjE[i]; s0 = a0.x; ae0 = __int_as_float(a0.y); }
        else s0 = adjP[i];
        uint2 p0 = ((const uint2*)(kv + (size_t)s0 * 32))[cp];
        float2 a00 = __half22float2(*(const __half2*)&p0.x);
        float2 a01 = __half22float2(*(const __half2*)&p0.y);
        float d0 = fmaf(qc.x, a00.x, qc.y * a01.x);
        d0 += __shfl_xor(d0, 8);
        d0 += __shfl_xor(d0, 4);
        d0 += __shfl_xor(d0, 2);
        d0 += __shfl_xor(d0, 1);
        float ex0 = __expf(fmaf(ae0, qd, d0 * RSQRT32));
        den0 += ex0;
        num0.x = fmaf(fmaf(ae0, uc.x, a00.y), ex0, num0.x);
        num0.y = fmaf(fmaf(ae0, uc.y, a01.y), ex0, num0.y);
    }
    float den = den0 + den1;
    float2 num = make_float2(num0.x + num1.x, num0.y + num1.y);
    den   += __shfl_xor(den, 16);   den   += __shfl_xor(den, 32);
    num.x += __shfl_xor(num.x, 16); num.x += __shfl_xor(num.x, 32);
    num.y += __shfl_xor(num.y, 16); num.y += __shfl_xor(num.y, 32);
    if (lane < 16) {
        float inv = 1.f / (den + 1e-16f);
        float2 sk = ((const float2*)(skp + (size_t)n * 32))[cp];
        float2 o;
        o.x = tanhf(fmaf(num.x, inv, sk.x));
        o.y = tanhf(fmaf(num.y, inv, sk.y));
        ((float2*)(xout + (size_t)n * 32))[cp] = o;
    }
}

// ---------------- per-layer pooling (coalesced; 1 atomic row per block) --------
__global__ void pool_kernel(const float* __restrict__ x,
                            const int* __restrict__ bstart, const int* __restrict__ bend,
                            float* __restrict__ poolsum, int layer_off) {
    __shared__ float red[256];
    int b = blockIdx.x >> 3, sub = blockIdx.x & 7;
    int s0 = bstart[b], s1 = bend[b];
    int cnt = s1 - s0;
    int n0 = s0 + (int)((long long)cnt * sub / 8);
    int n1 = s0 + (int)((long long)cnt * (sub + 1) / 8);
    int t = threadIdx.x, col = t & 31, g = t >> 5;
    float acc = 0.f;
    for (int n = n0 + g; n < n1; n += 8)
        acc += x[(size_t)n * 32 + col];
    red[t] = acc;
    __syncthreads();
    if (t < 32) {
        float s = red[t];
        #pragma unroll
        for (int k = 1; k < 8; ++k) s += red[t + 32 * k];
        atomicAdd(&poolsum[(size_t)b * 288 + layer_off + t], s);
    }
}

// ---------------- head ----------------

__device__ __forceinline__ void gemv_step(const float* __restrict__ W, const float* __restrict__ bias,
    const float* sin_, float* sout, int K, int M, int t, bool do_relu) {
    if (t < M) {
        float acc = bias[t];
        for (int kk = 0; kk < K; ++kk) acc = fmaf(sin_[kk], W[kk * M + t], acc);
        sout[t] = do_relu ? fmaxf(acc, 0.f) : acc;
    }
    __syncthreads();
}

// One block per graph. (mean-pool commutes with W1: mean(s@W1+b1) = mean(s)@W1+b1)
__global__ void head_kernel(const float* __restrict__ poolsum,
    const int* __restrict__ bstart, const int* __restrict__ bend,
    const float* __restrict__ W1, const float* __restrict__ b1,
    const float* __restrict__ W2, const float* __restrict__ b2,
    const float* __restrict__ W3, const float* __restrict__ b3,
    const float* __restrict__ W4, const float* __restrict__ b4,
    const float* __restrict__ W5, const float* __restrict__ b5,
    const float* __restrict__ W6, const float* __restrict__ b6,
    float* __restrict__ out)
{
    __shared__ float ha[288], hb[288];
    __shared__ float lse;
    int b = blockIdx.x, t = threadIdx.x;
    float invc = 1.f / fmaxf((float)(bend[b] - bstart[b]), 1.f);
    if (t < 288) ha[t] = poolsum[(size_t)b * 288 + t] * invc;
    __syncthreads();
    gemv_step(W1, b1, ha, hb, 288, 288, t, false);
    gemv_step(W2, b2, hb, ha, 288, 144, t, true);
    gemv_step(W3, b3, ha, hb, 144, 144, t, false);
    gemv_step(W4, b4, hb, ha, 144, 72,  t, false);
    gemv_step(W5, b5, ha, hb, 72,  72,  t, false);
    gemv_step(W6, b6, hb, ha, 72,  10,  t, false);
    if (t == 0) {
        float m = ha[0];
        for (int i = 1; i < 10; ++i) m = fmaxf(m, ha[i]);
        float ssum = 0.f;
        for (int i = 0; i < 10; ++i) ssum += __expf(ha[i] - m);
        lse = m + logf(ssum);
    }
    __syncthreads();
    if (t < 10) out[b * 10 + t] = ha[t] - lse;
}

// ---------------- launch ----------------

extern "C" void kernel_launch(void* const* d_in, const int* in_sizes, int n_in,
                              void* d_out, int out_size, void* d_ws, size_t ws_size,
                              hipStream_t stream)
{
    const float* inter_emb = (const float*)d_in[0];
    const float* edge_attr = (const float*)d_in[1];
    const float* uv_emb    = (const float*)d_in[2];
    const int* inter_idx = (const int*)d_in[3];
    const int* uvt_idx   = (const int*)d_in[4];
    const int* tuv_idx   = (const int*)d_in[5];
    const int* batch     = (const int*)d_in[6];
    const float* cWq = (const float*)d_in[7];  const float* cbq = (const float*)d_in[8];
    const float* cWk = (const float*)d_in[9];  const float* cbk = (const float*)d_in[10];
    const float* cWv = (const float*)d_in[11]; const float* cbv = (const float*)d_in[12];
    const float* cWs = (const float*)d_in[13]; const float* cbs = (const float*)d_in[14];
    const float* cWe = (const float*)d_in[15];
    const float* W1 = (const float*)d_in[16]; const float* b1 = (const float*)d_in[17];
    const float* W2 = (const float*)d_in[18]; const float* b2 = (const float*)d_in[19];
    const float* W3 = (const float*)d_in[20]; const float* b3 = (const float*)d_in[21];
    const float* W4 = (const float*)d_in[22]; const float* b4 = (const float*)d_in[23];
    const float* W5 = (const float*)d_in[24]; const float* b5 = (const float*)d_in[25];
    const float* W6 = (const float*)d_in[26]; const float* b6 = (const float*)d_in[27];

    const int N = in_sizes[2] / 32;
    const int E = in_sizes[1];
    const int B = out_size / 10;
    const int G = (N + TILE - 1) / TILE;
    const int BS = (N + NS - 1) / NS;      // bins per slice (<= MAXBS)
    const int CH = (E + NC - 1) / NC;      // edges per chunk

    char* p = (char*)d_ws;
    auto alloc = [&](size_t bytes) { char* r = p; p += (bytes + 255) & ~(size_t)255; return r; };
    float*   qb    = (float*)alloc((size_t)N * 32 * 4);
    __half2* kv    = (__half2*)alloc((size_t)N * 32 * 4);   // half2(k,v) per channel
    float*   sb    = (float*)alloc((size_t)N * 32 * 4);
    float*   qdu   = (float*)alloc((size_t)N * 4);
    float*   xa    = (float*)alloc((size_t)N * 32 * 4);
    float*   xb    = (float*)alloc((size_t)N * 32 * 4);
    float*   ub    = (float*)alloc(96 * 4);
    float*   poolsum = (float*)alloc((size_t)B * 288 * 4);
    int*     bstart = (int*)alloc((size_t)B * 4);
    int*     bend   = (int*)alloc((size_t)B * 4);
    int*     cnt3  = (int*)alloc((size_t)3 * N * 4);
    int*     rp3   = (int*)alloc((size_t)3 * (N + 1) * 4);
    int*     tsum  = (int*)alloc((size_t)3 * G * 4);
    unsigned int* partial = (unsigned int*)alloc((size_t)3 * NS * NC * BS * 4);
    int2*    adj0  = (int2*)alloc((size_t)E * 8);
    int*     adj12 = (int*)alloc((size_t)2 * E * 4);

    // ---- CSR build: counting sort, no global atomics ----
    hist_lds<<<3 * NS * NC, 256, 0, stream>>>(inter_idx, uvt_idx, tuv_idx, E, N, BS, CH, partial);
    chunk_scan<<<(3 * NS * BS + 255) / 256, 256, 0, stream>>>(partial, cnt3, N, BS);
    scan_tiles_sum<<<3 * G, 256, 0, stream>>>(cnt3, tsum, N, G);
    scan_offsets<<<1, 64, 0, stream>>>(tsum, rp3, N, G);
    scan_write<<<3 * G, 256, 0, stream>>>(cnt3, tsum, rp3, N, G);
    scatter_cs<<<3 * NS * NC, 256, 0, stream>>>(inter_idx, uvt_idx, tuv_idx, edge_attr,
                                                partial, rp3, adj0, adj12, E, N, BS, CH);

    hipMemsetAsync(poolsum, 0, (size_t)B * 288 * 4, stream);
    hipMemsetAsync(bstart, 0, (size_t)B * 4, stream);
    hipMemsetAsync(bend, 0, (size_t)B * 4, stream);
    colsum_kernel<<<1, 128, 0, stream>>>(cWe, ub);
    bounds_kernel<<<(N + 255) / 256, 256, 0, stream>>>(batch, bstart, bend, N);

    float* xcur = nullptr;
    float* xnext = xa;
    for (int i = 0; i < 9; ++i) {
        int r = i % 3;
        const float* xsrc; int ssrc; const float* xdst; int sdst;
        if (i == 0)      { xsrc = inter_emb; ssrc = 64; xdst = inter_emb + 32; sdst = 64; }
        else if (r == 0) { xsrc = xcur; ssrc = 32; xdst = xcur;  sdst = 32; }
        else if (r == 1) { xsrc = xcur; ssrc = 32; xdst = uv_emb; sdst = 32; }
        else             { xsrc = uv_emb; ssrc = 32; xdst = xcur; sdst = 32; }
        const float* ul = (r == 0) ? (ub + (i / 3) * 32) : nullptr;

        qkvs_kernel<<<1024, 256, 0, stream>>>(xsrc, ssrc, xdst, sdst,
            cWq + i * 1024, cbq + i * 32, cWk + i * 1024, cbk + i * 32,
            cWv + i * 1024, cbv + i * 32, cWs + i * 1024, cbs + i * 32,
            ul, qb, kv, sb, qdu, N);
        const int* rpl = rp3 + (size_t)r * (N + 1);
        if (r == 0) {
            agg_kernel<1><<<(N + 3) / 4, 256, 0, stream>>>(
                rpl, adj0, qb, kv, qdu, ul, sb, xnext, N);
        } else {
            agg_kernel<0><<<(N + 3) / 4, 256, 0, stream>>>(
                rpl, adj12 + (size_t)(r - 1) * E, qb, kv, qdu, ul, sb, xnext, N);
        }
        pool_kernel<<<B * 8, 256, 0, stream>>>(xnext, bstart, bend, poolsum, i * 32);
        xcur = xnext;
        xnext = (xnext == xa) ? xb : xa;
    }

    head_kernel<<<B, 320, 0, stream>>>(poolsum, bstart, bend,
        W1, b1, W2, b2, W3, b3, W4, b4, W5, b5, W6, b6, (float*)d_out);
}

// Round 7
// 623.384 us; speedup vs baseline: 13.3664x; 1.0006x over previous
//
#include <hip/hip_runtime.h>
#include <hip/hip_fp16.h>
#include <math.h>

#define RSQRT32 0.17677669529663687f
#define NS 8          // dst slices (LDS histogram fits: 6336*4 = 25 KB)
#define NC 32         // edge chunks per relation
#define MAXBS 6336    // max bins per slice (N=50000 -> BS=6250)
#define TILE 2048

// ---------------- CSR build: atomic-free counting sort ----------------

// Pass 1: per-(relation, slice, chunk) LDS histogram -> partial counts.
__global__ void hist_lds(const int* __restrict__ e0, const int* __restrict__ e1,
                         const int* __restrict__ e2, int E, int N, int BS, int CH,
                         unsigned int* __restrict__ partial) {
    __shared__ unsigned int h[MAXBS];
    int blk = blockIdx.x;
    int c = blk % NC, s = (blk / NC) % NS, r = blk / (NC * NS);
    int lo = s * BS, hi = min(lo + BS, N), nb = hi - lo;
    for (int i = threadIdx.x; i < nb; i += 256) h[i] = 0;
    __syncthreads();
    const int* ei = (r == 0) ? e0 : ((r == 1) ? e1 : e2);
    int ebeg = c * CH, eend = min(ebeg + CH, E);
    const int* dst = ei + E;
    for (int i = ebeg + (int)threadIdx.x; i < eend; i += 256) {
        int d = dst[i];
        if (d >= lo && d < hi) atomicAdd(&h[d - lo], 1u);
    }
    __syncthreads();
    unsigned int* out = partial + ((size_t)blk) * BS;
    for (int i = threadIdx.x; i < nb; i += 256) out[i] = h[i];
}

// Pass 2: per-bin exclusive scan over chunks (in place) + per-dst totals -> cnt3.
__global__ void chunk_scan(unsigned int* __restrict__ partial, int* __restrict__ cnt3,
                           int N, int BS) {
    int t = blockIdx.x * blockDim.x + threadIdx.x;
    int tot = 3 * NS * BS;
    if (t >= tot) return;
    int r = t / (NS * BS);
    int rem = t - r * NS * BS;
    int s = rem / BS, bin = rem - s * BS;
    int d = s * BS + bin;
    if (d >= N) return;
    size_t base = ((size_t)(r * NS + s) * NC) * BS + bin;
    unsigned int run = 0;
    for (int c = 0; c < NC; ++c) {
        unsigned int v = partial[base + (size_t)c * BS];
        partial[base + (size_t)c * BS] = run;
        run += v;
    }
    cnt3[(size_t)r * N + d] = (int)run;
}

// Coalesced two-level scan of cnt3 -> rp3 (row pointers).
__global__ void scan_tiles_sum(const int* __restrict__ cnt3, int* __restrict__ tsum,
                               int N, int G) {
    int blk = blockIdx.x, r = blk / G, g = blk - r * G;
    int base = g * TILE;
    const int* cnt = cnt3 + (size_t)r * N;
    int s = 0;
    for (int i = threadIdx.x; i < TILE; i += 256) {
        int idx = base + i;
        s += (idx < N) ? cnt[idx] : 0;
    }
    __shared__ int wsum[4];
    for (int m = 32; m; m >>= 1) s += __shfl_down(s, m);
    if ((threadIdx.x & 63) == 0) wsum[threadIdx.x >> 6] = s;
    __syncthreads();
    if (threadIdx.x == 0) tsum[blk] = wsum[0] + wsum[1] + wsum[2] + wsum[3];
}

__global__ void scan_offsets(int* __restrict__ tsum, int* __restrict__ rp3, int N, int G) {
    int r = threadIdx.x;
    if (r < 3) {
        int run = 0;
        for (int g = 0; g < G; ++g) { int v = tsum[r * G + g]; tsum[r * G + g] = run; run += v; }
        rp3[(size_t)r * (N + 1) + N] = run;
    }
}

__global__ void scan_write(const int* __restrict__ cnt3, const int* __restrict__ toff,
                           int* __restrict__ rp3, int N, int G) {
    int blk = blockIdx.x, r = blk / G, g = blk - r * G;
    int base = g * TILE;
    const int* cnt = cnt3 + (size_t)r * N;
    int* rp = rp3 + (size_t)r * (N + 1);
    __shared__ int part[256];
    int t = threadIdx.x;
    int v[8]; int s = 0;
    #pragma unroll
    for (int j = 0; j < 8; ++j) {
        int idx = base + t * 8 + j;
        int x = (idx < N) ? cnt[idx] : 0;
        v[j] = s; s += x;
    }
    part[t] = s;
    __syncthreads();
    for (int off = 1; off < 256; off <<= 1) {
        int x = (t >= off) ? part[t - off] : 0;
        __syncthreads();
        part[t] += x;
        __syncthreads();
    }
    int texcl = part[t] - s + toff[blk];
    #pragma unroll
    for (int j = 0; j < 8; ++j) {
        int idx = base + t * 8 + j;
        if (idx < N) rp[idx] = texcl + v[j];
    }
}

// Pass 3: scatter via LDS cursors; no global atomics.
// XCD-aligned: slice = blk&7 so all 32 chunk-blocks of one slice run on one XCD
// (round-robin block->XCD) -> partial-line writes to the slice's adj region merge
// in that XCD's L2 before writeback.
__global__ void scatter_cs(const int* __restrict__ e0, const int* __restrict__ e1,
                           const int* __restrict__ e2, const float* __restrict__ ea,
                           const unsigned int* __restrict__ partial,
                           const int* __restrict__ rp3,
                           int2* __restrict__ adj0, int* __restrict__ adj12,
                           int E, int N, int BS, int CH) {
    __shared__ unsigned int cur[MAXBS];
    int blk = blockIdx.x;
    int s = blk & 7;
    int rest = blk >> 3;
    int c = rest % NC, r = rest / NC;
    int pblk = c + NC * (s + NS * r);     // partial-buffer index (hist layout)
    int lo = s * BS, hi = min(lo + BS, N), nb = hi - lo;
    const unsigned int* po = partial + ((size_t)pblk) * BS;
    const int* rp = rp3 + (size_t)r * (N + 1);
    for (int i = threadIdx.x; i < nb; i += 256)
        cur[i] = (unsigned int)rp[lo + i] + po[i];
    __syncthreads();
    const int* ei = (r == 0) ? e0 : ((r == 1) ? e1 : e2);
    const int* srcp = ei;
    const int* dstp = ei + E;
    int ebeg = c * CH, eend = min(ebeg + CH, E);
    if (r == 0) {
        for (int i = ebeg + (int)threadIdx.x; i < eend; i += 256) {
            int d = dstp[i];
            if (d < lo || d >= hi) continue;
            unsigned int pos = atomicAdd(&cur[d - lo], 1u);
            int2 v; v.x = srcp[i]; v.y = __float_as_int(ea[i]);
            adj0[pos] = v;
        }
    } else {
        int* adj = adj12 + (size_t)(r - 1) * E;
        for (int i = ebeg + (int)threadIdx.x; i < eend; i += 256) {
            int d = dstp[i];
            if (d < lo || d >= hi) continue;
            unsigned int pos = atomicAdd(&cur[d - lo], 1u);
            adj[pos] = srcp[i];
        }
    }
}

// ---------------- misc small kernels ----------------

__global__ void colsum_kernel(const float* __restrict__ We, float* __restrict__ u) {
    int t = threadIdx.x;
    if (t < 96) {
        int w = t >> 5, j = t & 31;
        const float* W = We + w * 1024;
        float s = 0.f;
        #pragma unroll
        for (int kk = 0; kk < 32; ++kk) s += W[kk * 32 + j];
        u[t] = s;
    }
}

// batch is sorted: graph bounds are run boundaries -> plain unique stores.
__global__ void bounds_kernel(const int* __restrict__ batch, int* __restrict__ bstart,
                              int* __restrict__ bend, int N) {
    int t = blockIdx.x * blockDim.x + threadIdx.x;
    if (t >= N) return;
    int b = batch[t];
    if (t == 0 || batch[t - 1] != b) bstart[b] = t;
    if (t == N - 1 || batch[t + 1] != b) bend[b] = t + 1;
}

// ---------------- per-layer: fused q,k,v,skip GEMMs (+qdotu) ----------------
// lanes 0-31: q (xd) & v (xs) columns; lanes 32-63: k (xs) & skip (xd) columns.
// kv packed fp16: kv[n][c] = half2(k_c, v_c) -> 128B row, 4B per channel.
__global__ void qkvs_kernel(
    const float* __restrict__ xs, int ssrc,
    const float* __restrict__ xd, int sdst,
    const float* __restrict__ Wq, const float* __restrict__ bq,
    const float* __restrict__ Wk, const float* __restrict__ bk,
    const float* __restrict__ Wv, const float* __restrict__ bv,
    const float* __restrict__ Ws, const float* __restrict__ bs,
    const float* __restrict__ u,      // nullptr for non-edge layers
    float* __restrict__ qb, __half2* __restrict__ kv,
    float* __restrict__ sb, float* __restrict__ qdu, int N)
{
    int lane = threadIdx.x & 63;
    int wid  = __builtin_amdgcn_readfirstlane((int)(threadIdx.x >> 6));
    int wpb  = blockDim.x >> 6;
    int gw   = blockIdx.x * wpb + wid;
    int nw   = gridDim.x * wpb;
    int j    = lane & 31;
    bool lower = lane < 32;

    const float* W1 = lower ? Wq : Wk;
    const float* W2 = lower ? Wv : Ws;
    float rw1[32], rw2[32];
    #pragma unroll
    for (int kk = 0; kk < 32; ++kk) {
        rw1[kk] = W1[kk * 32 + j];
        rw2[kk] = W2[kk * 32 + j];
    }
    float bias1 = lower ? bq[j] : bk[j];
    float bias2 = lower ? bv[j] : bs[j];
    float uj = (u != nullptr) ? u[j] : 0.f;

    for (int n = gw; n < N; n += nw) {
        const float* xdr = xd + (size_t)n * sdst;  // wave-uniform -> scalar loads
        const float* xsr = xs + (size_t)n * ssrc;
        float acc1 = bias1, acc2 = bias2;
        #pragma unroll
        for (int kk = 0; kk < 32; ++kk) {
            float xdv = xdr[kk];
            float xsv = xsr[kk];
            float a  = lower ? xdv : xsv;   // q | k input
            float bb = lower ? xsv : xdv;   // v | skip input
            acc1 = fmaf(a,  rw1[kk], acc1);
            acc2 = fmaf(bb, rw2[kk], acc2);
        }
        float kk_ = __shfl(acc1, j + 32);   // k_j from upper half
        if (lower) {
            qb[(size_t)n * 32 + j] = acc1;                  // q
            kv[(size_t)n * 32 + j] = __floats2half2_rn(kk_, acc2);  // (k, v)
        } else {
            sb[(size_t)n * 32 + j] = acc2;                  // skip
        }
        if (u != nullptr) {
            float pp = lower ? acc1 * uj : 0.f;
            pp += __shfl_xor(pp, 16);
            pp += __shfl_xor(pp, 8);
            pp += __shfl_xor(pp, 4);
            pp += __shfl_xor(pp, 2);
            pp += __shfl_xor(pp, 1);
            if (lane == 0) qdu[n] = pp * RSQRT32;
        }
    }
}

// ---------------- per-layer: gather-side aggregation (pure, no atomics) -------
// One wave per dst node. Octet layout: 8 lanes/edge, lane cq owns channels
// 4cq..4cq+3 (uint4 = 128B coalesced row read). 8 edge streams x 2-way ILP
// = 16 edges in flight per wave; 3-step shfl dot reduce.
template<int HAS_EA>
__global__ __launch_bounds__(256, 8)
void agg_kernel(const int* __restrict__ rp, const void* __restrict__ adjv,
    const float* __restrict__ qb, const __half2* __restrict__ kv,
    const float* __restrict__ qdu, const float* __restrict__ u,
    const float* __restrict__ skp, float* __restrict__ xout, int N)
{
    int t = threadIdx.x;
    int w = t >> 6, lane = t & 63;
    int cq = lane & 7;        // channel quad
    int o  = lane >> 3;       // octet (edge stream)
    int n = blockIdx.x * 4 + w;
    if (n >= N) return;
    float4 qc = ((const float4*)(qb + (size_t)n * 32))[cq];
    float qd = HAS_EA ? qdu[n] : 0.f;
    float4 uc = HAS_EA ? ((const float4*)u)[cq] : make_float4(0.f, 0.f, 0.f, 0.f);
    int beg = rp[n], end = rp[n + 1];
    float den0 = 0.f, den1 = 0.f;
    float4 num0 = make_float4(0.f, 0.f, 0.f, 0.f);
    float4 num1 = make_float4(0.f, 0.f, 0.f, 0.f);
    const int2* adjE = (const int2*)adjv;
    const int*  adjP = (const int*)adjv;
    int i = beg + o;
    for (; i + 8 < end; i += 16) {
        int s0, s1; float ae0 = 0.f, ae1 = 0.f;
        if (HAS_EA) {
            int2 a0 = adjE[i], a1 = adjE[i + 8];
            s0 = a0.x; s1 = a1.x;
            ae0 = __int_as_float(a0.y); ae1 = __int_as_float(a1.y);
        } else { s0 = adjP[i]; s1 = adjP[i + 8]; }
        uint4 p0 = ((const uint4*)(kv + (size_t)s0 * 32))[cq];
        uint4 p1 = ((const uint4*)(kv + (size_t)s1 * 32))[cq];
        float2 a00 = __half22float2(*(const __half2*)&p0.x);
        float2 a01 = __half22float2(*(const __half2*)&p0.y);
        float2 a02 = __half22float2(*(const __half2*)&p0.z);
        float2 a03 = __half22float2(*(const __half2*)&p0.w);
        float2 a10 = __half22float2(*(const __half2*)&p1.x);
        float2 a11 = __half22float2(*(const __half2*)&p1.y);
        float2 a12 = __half22float2(*(const __half2*)&p1.z);
        float2 a13 = __half22float2(*(const __half2*)&p1.w);
        float d0 = fmaf(qc.x, a00.x, fmaf(qc.y, a01.x, fmaf(qc.z, a02.x, qc.w * a03.x)));
        float d1 = fmaf(qc.x, a10.x, fmaf(qc.y, a11.x, fmaf(qc.z, a12.x, qc.w * a13.x)));
        d0 += __shfl_xor(d0, 4);  d1 += __shfl_xor(d1, 4);
        d0 += __shfl_xor(d0, 2);  d1 += __shfl_xor(d1, 2);
        d0 += __shfl_xor(d0, 1);  d1 += __shfl_xor(d1, 1);
        // softmax is shift-invariant; logits O(+-7) so direct exp is safe
        float ex0 = __expf(fmaf(ae0, qd, d0 * RSQRT32));
        float ex1 = __expf(fmaf(ae1, qd, d1 * RSQRT32));
        den0 += ex0;  den1 += ex1;
        num0.x = fmaf(fmaf(ae0, uc.x, a00.y), ex0, num0.x);
        num0.y = fmaf(fmaf(ae0, uc.y, a01.y), ex0, num0.y);
        num0.z = fmaf(fmaf(ae0, uc.z, a02.y), ex0, num0.z);
        num0.w = fmaf(fmaf(ae0, uc.w, a03.y), ex0, num0.w);
        num1.x = fmaf(fmaf(ae1, uc.x, a10.y), ex1, num1.x);
        num1.y = fmaf(fmaf(ae1, uc.y, a11.y), ex1, num1.y);
        num1.z = fmaf(fmaf(ae1, uc.z, a12.y), ex1, num1.z);
        num1.w = fmaf(fmaf(ae1, uc.w, a13.y), ex1, num1.w);
    }
    for (; i < end; i += 8) {
        int s0; float ae0 = 0.f;
        if (HAS_EA) { int2 a0 = adjE[i]; s0 = a0.x; ae0 = __int_as_float(a0.y); }
        else s0 = adjP[i];
        uint4 p0 = ((const uint4*)(kv + (size_t)s0 * 32))[cq];
        float2 a00 = __half22float2(*(const __half2*)&p0.x);
        float2 a01 = __half22float2(*(const __half2*)&p0.y);
        float2 a02 = __half22float2(*(const __half2*)&p0.z);
        float2 a03 = __half22float2(*(const __half2*)&p0.w);
        float d0 = fmaf(qc.x, a00.x, fmaf(qc.y, a01.x, fmaf(qc.z, a02.x, qc.w * a03.x)));
        d0 += __shfl_xor(d0, 4);
        d0 += __shfl_xor(d0, 2);
        d0 += __shfl_xor(d0, 1);
        float ex0 = __expf(fmaf(ae0, qd, d0 * RSQRT32));
        den0 += ex0;
        num0.x = fmaf(fmaf(ae0, uc.x, a00.y), ex0, num0.x);
        num0.y = fmaf(fmaf(ae0, uc.y, a01.y), ex0, num0.y);
        num0.z = fmaf(fmaf(ae0, uc.z, a02.y), ex0, num0.z);
        num0.w = fmaf(fmaf(ae0, uc.w, a03.y), ex0, num0.w);
    }
    float den = den0 + den1;
    float4 num = make_float4(num0.x + num1.x, num0.y + num1.y,
                             num0.z + num1.z, num0.w + num1.w);
    den   += __shfl_xor(den, 8);   den   += __shfl_xor(den, 16);   den   += __shfl_xor(den, 32);
    num.x += __shfl_xor(num.x, 8); num.x += __shfl_xor(num.x, 16); num.x += __shfl_xor(num.x, 32);
    num.y += __shfl_xor(num.y, 8); num.y += __shfl_xor(num.y, 16); num.y += __shfl_xor(num.y, 32);
    num.z += __shfl_xor(num.z, 8); num.z += __shfl_xor(num.z, 16); num.z += __shfl_xor(num.z, 32);
    num.w += __shfl_xor(num.w, 8); num.w += __shfl_xor(num.w, 16); num.w += __shfl_xor(num.w, 32);
    if (o == 0) {
        float inv = 1.f / (den + 1e-16f);
        float4 sk = ((const float4*)(skp + (size_t)n * 32))[cq];
        float4 ov;
        ov.x = tanhf(fmaf(num.x, inv, sk.x));
        ov.y = tanhf(fmaf(num.y, inv, sk.y));
        ov.z = tanhf(fmaf(num.z, inv, sk.z));
        ov.w = tanhf(fmaf(num.w, inv, sk.w));
        ((float4*)(xout + (size_t)n * 32))[cq] = ov;
    }
}

// ---------------- per-layer pooling (coalesced; 1 atomic row per block) --------
__global__ void pool_kernel(const float* __restrict__ x,
                            const int* __restrict__ bstart, const int* __restrict__ bend,
                            float* __restrict__ poolsum, int layer_off) {
    __shared__ float red[256];
    int b = blockIdx.x >> 3, sub = blockIdx.x & 7;
    int s0 = bstart[b], s1 = bend[b];
    int cnt = s1 - s0;
    int n0 = s0 + (int)((long long)cnt * sub / 8);
    int n1 = s0 + (int)((long long)cnt * (sub + 1) / 8);
    int t = threadIdx.x, col = t & 31, g = t >> 5;
    float acc = 0.f;
    for (int n = n0 + g; n < n1; n += 8)
        acc += x[(size_t)n * 32 + col];
    red[t] = acc;
    __syncthreads();
    if (t < 32) {
        float s = red[t];
        #pragma unroll
        for (int k = 1; k < 8; ++k) s += red[t + 32 * k];
        atomicAdd(&poolsum[(size_t)b * 288 + layer_off + t], s);
    }
}

// ---------------- head ----------------

__device__ __forceinline__ void gemv_step(const float* __restrict__ W, const float* __restrict__ bias,
    const float* sin_, float* sout, int K, int M, int t, bool do_relu) {
    if (t < M) {
        float acc = bias[t];
        for (int kk = 0; kk < K; ++kk) acc = fmaf(sin_[kk], W[kk * M + t], acc);
        sout[t] = do_relu ? fmaxf(acc, 0.f) : acc;
    }
    __syncthreads();
}

// One block per graph. (mean-pool commutes with W1: mean(s@W1+b1) = mean(s)@W1+b1)
__global__ void head_kernel(const float* __restrict__ poolsum,
    const int* __restrict__ bstart, const int* __restrict__ bend,
    const float* __restrict__ W1, const float* __restrict__ b1,
    const float* __restrict__ W2, const float* __restrict__ b2,
    const float* __restrict__ W3, const float* __restrict__ b3,
    const float* __restrict__ W4, const float* __restrict__ b4,
    const float* __restrict__ W5, const float* __restrict__ b5,
    const float* __restrict__ W6, const float* __restrict__ b6,
    float* __restrict__ out)
{
    __shared__ float ha[288], hb[288];
    __shared__ float lse;
    int b = blockIdx.x, t = threadIdx.x;
    float invc = 1.f / fmaxf((float)(bend[b] - bstart[b]), 1.f);
    if (t < 288) ha[t] = poolsum[(size_t)b * 288 + t] * invc;
    __syncthreads();
    gemv_step(W1, b1, ha, hb, 288, 288, t, false);
    gemv_step(W2, b2, hb, ha, 288, 144, t, true);
    gemv_step(W3, b3, ha, hb, 144, 144, t, false);
    gemv_step(W4, b4, hb, ha, 144, 72,  t, false);
    gemv_step(W5, b5, ha, hb, 72,  72,  t, false);
    gemv_step(W6, b6, hb, ha, 72,  10,  t, false);
    if (t == 0) {
        float m = ha[0];
        for (int i = 1; i < 10; ++i) m = fmaxf(m, ha[i]);
        float ssum = 0.f;
        for (int i = 0; i < 10; ++i) ssum += __expf(ha[i] - m);
        lse = m + logf(ssum);
    }
    __syncthreads();
    if (t < 10) out[b * 10 + t] = ha[t] - lse;
}

// ---------------- launch ----------------

extern "C" void kernel_launch(void* const* d_in, const int* in_sizes, int n_in,
                              void* d_out, int out_size, void* d_ws, size_t ws_size,
                              hipStream_t stream)
{
    const float* inter_emb = (const float*)d_in[0];
    const float* edge_attr = (const float*)d_in[1];
    const float* uv_emb    = (const float*)d_in[2];
    const int* inter_idx = (const int*)d_in[3];
    const int* uvt_idx   = (const int*)d_in[4];
    const int* tuv_idx   = (const int*)d_in[5];
    const int* batch     = (const int*)d_in[6];
    const float* cWq = (const float*)d_in[7];  const float* cbq = (const float*)d_in[8];
    const float* cWk = (const float*)d_in[9];  const float* cbk = (const float*)d_in[10];
    const float* cWv = (const float*)d_in[11]; const float* cbv = (const float*)d_in[12];
    const float* cWs = (const float*)d_in[13]; const float* cbs = (const float*)d_in[14];
    const float* cWe = (const float*)d_in[15];
    const float* W1 = (const float*)d_in[16]; const float* b1 = (const float*)d_in[17];
    const float* W2 = (const float*)d_in[18]; const float* b2 = (const float*)d_in[19];
    const float* W3 = (const float*)d_in[20]; const float* b3 = (const float*)d_in[21];
    const float* W4 = (const float*)d_in[22]; const float* b4 = (const float*)d_in[23];
    const float* W5 = (const float*)d_in[24]; const float* b5 = (const float*)d_in[25];
    const float* W6 = (const float*)d_in[26]; const float* b6 = (const float*)d_in[27];

    const int N = in_sizes[2] / 32;
    const int E = in_sizes[1];
    const int B = out_size / 10;
    const int G = (N + TILE - 1) / TILE;
    const int BS = (N + NS - 1) / NS;      // bins per slice (<= MAXBS)
    const int CH = (E + NC - 1) / NC;      // edges per chunk

    char* p = (char*)d_ws;
    auto alloc = [&](size_t bytes) { char* r = p; p += (bytes + 255) & ~(size_t)255; return r; };
    float*   qb    = (float*)alloc((size_t)N * 32 * 4);
    __half2* kv    = (__half2*)alloc((size_t)N * 32 * 4);   // half2(k,v) per channel
    float*   sb    = (float*)alloc((size_t)N * 32 * 4);
    float*   qdu   = (float*)alloc((size_t)N * 4);
    float*   xa    = (float*)alloc((size_t)N * 32 * 4);
    float*   xb    = (float*)alloc((size_t)N * 32 * 4);
    float*   ub    = (float*)alloc(96 * 4);
    float*   poolsum = (float*)alloc((size_t)B * 288 * 4);
    int*     bstart = (int*)alloc((size_t)B * 4);
    int*     bend   = (int*)alloc((size_t)B * 4);
    int*     cnt3  = (int*)alloc((size_t)3 * N * 4);
    int*     rp3   = (int*)alloc((size_t)3 * (N + 1) * 4);
    int*     tsum  = (int*)alloc((size_t)3 * G * 4);
    unsigned int* partial = (unsigned int*)alloc((size_t)3 * NS * NC * BS * 4);
    int2*    adj0  = (int2*)alloc((size_t)E * 8);
    int*     adj12 = (int*)alloc((size_t)2 * E * 4);

    // ---- CSR build: counting sort, no global atomics ----
    hist_lds<<<3 * NS * NC, 256, 0, stream>>>(inter_idx, uvt_idx, tuv_idx, E, N, BS, CH, partial);
    chunk_scan<<<(3 * NS * BS + 255) / 256, 256, 0, stream>>>(partial, cnt3, N, BS);
    scan_tiles_sum<<<3 * G, 256, 0, stream>>>(cnt3, tsum, N, G);
    scan_offsets<<<1, 64, 0, stream>>>(tsum, rp3, N, G);
    scan_write<<<3 * G, 256, 0, stream>>>(cnt3, tsum, rp3, N, G);
    scatter_cs<<<3 * NS * NC, 256, 0, stream>>>(inter_idx, uvt_idx, tuv_idx, edge_attr,
                                                partial, rp3, adj0, adj12, E, N, BS, CH);

    hipMemsetAsync(poolsum, 0, (size_t)B * 288 * 4, stream);
    hipMemsetAsync(bstart, 0, (size_t)B * 4, stream);
    hipMemsetAsync(bend, 0, (size_t)B * 4, stream);
    colsum_kernel<<<1, 128, 0, stream>>>(cWe, ub);
    bounds_kernel<<<(N + 255) / 256, 256, 0, stream>>>(batch, bstart, bend, N);

    float* xcur = nullptr;
    float* xnext = xa;
    for (int i = 0; i < 9; ++i) {
        int r = i % 3;
        const float* xsrc; int ssrc; const float* xdst; int sdst;
        if (i == 0)      { xsrc = inter_emb; ssrc = 64; xdst = inter_emb + 32; sdst = 64; }
        else if (r == 0) { xsrc = xcur; ssrc = 32; xdst = xcur;  sdst = 32; }
        else if (r == 1) { xsrc = xcur; ssrc = 32; xdst = uv_emb; sdst = 32; }
        else             { xsrc = uv_emb; ssrc = 32; xdst = xcur; sdst = 32; }
        const float* ul = (r == 0) ? (ub + (i / 3) * 32) : nullptr;

        qkvs_kernel<<<1024, 256, 0, stream>>>(xsrc, ssrc, xdst, sdst,
            cWq + i * 1024, cbq + i * 32, cWk + i * 1024, cbk + i * 32,
            cWv + i * 1024, cbv + i * 32, cWs + i * 1024, cbs + i * 32,
            ul, qb, kv, sb, qdu, N);
        const int* rpl = rp3 + (size_t)r * (N + 1);
        if (r == 0) {
            agg_kernel<1><<<(N + 3) / 4, 256, 0, stream>>>(
                rpl, adj0, qb, kv, qdu, ul, sb, xnext, N);
        } else {
            agg_kernel<0><<<(N + 3) / 4, 256, 0, stream>>>(
                rpl, adj12 + (size_t)(r - 1) * E, qb, kv, qdu, ul, sb, xnext, N);
        }
        pool_kernel<<<B * 8, 256, 0, stream>>>(xnext, bstart, bend, poolsum, i * 32);
        xcur = xnext;
        xnext = (xnext == xa) ? xb : xa;
    }

    head_kernel<<<B, 320, 0, stream>>>(poolsum, bstart, bend,
        W1, b1, W2, b2, W3, b3, W4, b4, W5, b5, W6, b6, (float*)d_out);
}